// Round 1
// baseline (8686.449 us; speedup 1.0000x reference)
//
#include <hip/hip_runtime.h>
#include <hip/hip_bf16.h>

#define DEVI __device__ __forceinline__

// ============================================================================
// Generic strided SGEMM:  C[m,n] = alpha * sum_k A[m,k] * W[n,k]  (+bias)(relu)(+R)
// A[m,k] at A + a_base + z*a_zs + m*a_rs + k*a_cs
// W[n,k] at W + w_base + z*w_zs + n*w_rs + k*w_cs
// C[m,n] at C + c_base + z*c_zs + m*c_rs + n ; R likewise with r_rs
// flags: 1=bias, 2=relu, 4=residual
// 128x128 tile, BK=8, 256 threads, 8x8 per thread.
// ============================================================================
__global__ __launch_bounds__(256) void gemm_k(
    const float* __restrict__ Ap, long long a_base, int a_rs, int a_cs, long long a_zs,
    const float* __restrict__ Wp, long long w_base, int w_rs, int w_cs, long long w_zs,
    const float* __restrict__ bias,
    const float* __restrict__ Rp, int r_rs, long long r_zs,
    float* __restrict__ Cp, long long c_base, int c_rs, long long c_zs,
    int M, int N, int K, float alpha, int flags)
{
  __shared__ float As[8][132];
  __shared__ float Bs[8][132];
  const int z = blockIdx.z;
  const float* A = Ap + a_base + (long long)z * a_zs;
  const float* W = Wp + w_base + (long long)z * w_zs;
  float* C = Cp + c_base + (long long)z * c_zs;
  const float* R = (flags & 4) ? (Rp + (long long)z * r_zs) : nullptr;

  const int bm = blockIdx.y * 128;
  const int bn = blockIdx.x * 128;
  const int tid = threadIdx.x;
  const int tx = tid & 15;      // n dim
  const int ty = tid >> 4;      // m dim
  const int srow = tid >> 1;    // staging row 0..127
  const int k4 = (tid & 1) * 4; // staging k offset {0,4}

  float acc[8][8];
#pragma unroll
  for (int i = 0; i < 8; ++i)
#pragma unroll
    for (int j = 0; j < 8; ++j) acc[i][j] = 0.f;

  const int am = bm + srow;
  const int wn = bn + srow;
  const bool am_ok = am < M;
  const bool wn_ok = wn < N;
  const long long aoff = (long long)(am_ok ? am : 0) * a_rs;
  const long long woff = (long long)(wn_ok ? wn : 0) * w_rs;

  for (int k0 = 0; k0 < K; k0 += 8) {
    if (a_cs == 1 && am_ok && (k0 + 8 <= K)) {
      float4 v = *(const float4*)(A + aoff + k0 + k4);
      As[k4+0][srow] = v.x; As[k4+1][srow] = v.y;
      As[k4+2][srow] = v.z; As[k4+3][srow] = v.w;
    } else {
#pragma unroll
      for (int j = 0; j < 4; ++j) {
        int kk = k0 + k4 + j;
        float va = 0.f;
        if (am_ok && kk < K) va = A[aoff + (long long)kk * a_cs];
        As[k4+j][srow] = va;
      }
    }
    if (w_cs == 1 && wn_ok && (k0 + 8 <= K)) {
      float4 v = *(const float4*)(W + woff + k0 + k4);
      Bs[k4+0][srow] = v.x; Bs[k4+1][srow] = v.y;
      Bs[k4+2][srow] = v.z; Bs[k4+3][srow] = v.w;
    } else {
#pragma unroll
      for (int j = 0; j < 4; ++j) {
        int kk = k0 + k4 + j;
        float vb = 0.f;
        if (wn_ok && kk < K) vb = W[woff + (long long)kk * w_cs];
        Bs[k4+j][srow] = vb;
      }
    }
    __syncthreads();
#pragma unroll
    for (int kk = 0; kk < 8; ++kk) {
      float af[8], bf[8];
      *(float4*)&af[0] = *(const float4*)&As[kk][ty*8];
      *(float4*)&af[4] = *(const float4*)&As[kk][ty*8+4];
      *(float4*)&bf[0] = *(const float4*)&Bs[kk][tx*4];      // cols bn+tx*4..+3
      *(float4*)&bf[4] = *(const float4*)&Bs[kk][64+tx*4];   // cols bn+64+tx*4..+3
#pragma unroll
      for (int i = 0; i < 8; ++i)
#pragma unroll
        for (int j = 0; j < 8; ++j)
          acc[i][j] = fmaf(af[i], bf[j], acc[i][j]);
    }
    __syncthreads();
  }

#pragma unroll
  for (int i = 0; i < 8; ++i) {
    int m = bm + ty*8 + i;
    if (m >= M) continue;
#pragma unroll
    for (int jg = 0; jg < 2; ++jg) {
#pragma unroll
      for (int j = 0; j < 4; ++j) {
        int n = bn + jg*64 + tx*4 + j;
        if (n >= N) continue;
        float v = acc[i][jg*4+j] * alpha;
        if (flags & 1) v += bias[n];
        if (flags & 2) v = fmaxf(v, 0.f);
        if (flags & 4) v += R[(long long)m * r_rs + n];
        C[(long long)m * c_rs + n] = v;
      }
    }
  }
}

// ============================================================================
// LayerNorm over E=512, optional fused add of up to 2 extra inputs, optional relu
// ============================================================================
__global__ __launch_bounds__(256) void ln_k(
    const float* __restrict__ in0, const float* __restrict__ in1, const float* __restrict__ in2,
    const float* __restrict__ g, const float* __restrict__ b,
    float* __restrict__ outp, int relu)
{
  __shared__ float red[8];
  const long long base = (long long)blockIdx.x * 512;
  const int tid = threadIdx.x;
  float x0 = in0[base + tid];
  float x1 = in0[base + tid + 256];
  if (in1) { x0 += in1[base + tid]; x1 += in1[base + tid + 256]; }
  if (in2) { x0 += in2[base + tid]; x1 += in2[base + tid + 256]; }
  float s = x0 + x1, q = x0*x0 + x1*x1;
#pragma unroll
  for (int off = 32; off > 0; off >>= 1) {
    s += __shfl_down(s, off, 64);
    q += __shfl_down(q, off, 64);
  }
  if ((tid & 63) == 0) { red[tid >> 6] = s; red[4 + (tid >> 6)] = q; }
  __syncthreads();
  if (tid == 0) {
    float S = red[0]+red[1]+red[2]+red[3];
    float Q = red[4]+red[5]+red[6]+red[7];
    float m = S * (1.f/512.f);
    float v = Q * (1.f/512.f) - m*m;
    red[0] = m; red[1] = rsqrtf(v + 1e-5f);
  }
  __syncthreads();
  float m = red[0], inv = red[1];
  float y0 = (x0 - m) * inv * g[tid]     + b[tid];
  float y1 = (x1 - m) * inv * g[tid+256] + b[tid+256];
  if (relu) { y0 = fmaxf(y0, 0.f); y1 = fmaxf(y1, 0.f); }
  outp[base + tid]       = y0;
  outp[base + tid + 256] = y1;
}

// ============================================================================
// Row softmax (in place), one block per row, S <= 1024
// ============================================================================
__global__ __launch_bounds__(256) void softmax_k(float* __restrict__ p, int S)
{
  __shared__ float red[8];
  float* r = p + (long long)blockIdx.x * S;
  const int tid = threadIdx.x;
  float vals[4];
  int cnt = 0;
  float mx = -3.0e38f;
  for (int e = tid; e < S; e += 256) { float v = r[e]; vals[cnt++] = v; mx = fmaxf(mx, v); }
#pragma unroll
  for (int off = 32; off > 0; off >>= 1) mx = fmaxf(mx, __shfl_down(mx, off, 64));
  if ((tid & 63) == 0) red[tid >> 6] = mx;
  __syncthreads();
  if (tid == 0) red[0] = fmaxf(fmaxf(red[0], red[1]), fmaxf(red[2], red[3]));
  __syncthreads();
  mx = red[0];
  float sum = 0.f;
  for (int i = 0; i < cnt; ++i) { vals[i] = expf(vals[i] - mx); sum += vals[i]; }
#pragma unroll
  for (int off = 32; off > 0; off >>= 1) sum += __shfl_down(sum, off, 64);
  if ((tid & 63) == 0) red[4 + (tid >> 6)] = sum;
  __syncthreads();
  if (tid == 0) red[4] = red[4]+red[5]+red[6]+red[7];
  __syncthreads();
  float inv = 1.f / red[4];
  cnt = 0;
  for (int e = tid; e < S; e += 256) r[e] = vals[cnt++] * inv;
}

__global__ __launch_bounds__(256) void softmax4_k(float* __restrict__ p, int rows)
{
  int i = blockIdx.x * 256 + threadIdx.x;
  if (i >= rows) return;
  float* r = p + (long long)i * 4;
  float m = fmaxf(fmaxf(r[0], r[1]), fmaxf(r[2], r[3]));
  float e0 = expf(r[0]-m), e1 = expf(r[1]-m), e2 = expf(r[2]-m), e3 = expf(r[3]-m);
  float inv = 1.f / (e0+e1+e2+e3);
  r[0] = e0*inv; r[1] = e1*inv; r[2] = e2*inv; r[3] = e3*inv;
}

__global__ __launch_bounds__(256) void add2_k(
    const float* __restrict__ a, const float* __restrict__ b, float* __restrict__ o, int n)
{
  int i = blockIdx.x * 256 + threadIdx.x;
  if (i < n) o[i] = a[i] + b[i];
}

DEVI float inv_sig(float x)
{
  x = fminf(fmaxf(x, 0.f), 1.f);
  float a = fmaxf(x, 1e-5f);
  float c = fmaxf(1.f - x, 1e-5f);
  return logf(a / c);
}

// sample-prep: rp_d = sigmoid(invsig(ref[n%900]) + offset[n/4, 2*(n%4)+c]),
// project through 7 cams, emit normalized coords + validity.
__global__ __launch_bounds__(256) void sample_prep_k(
    const float* __restrict__ ref, const float* __restrict__ offs,
    const float* __restrict__ proj, float* __restrict__ camxy, float* __restrict__ valid)
{
  int n = blockIdx.x * 256 + threadIdx.x;
  if (n >= 3600) return;
  int qq = n >> 2, pp = n & 3;
  int rrow = n % 900;
  float tx = inv_sig(ref[rrow*2+0]) + offs[qq*8 + pp*2 + 0];
  float ty = inv_sig(ref[rrow*2+1]) + offs[qq*8 + pp*2 + 1];
  float sx = 1.f / (1.f + expf(-tx));
  float sy = 1.f / (1.f + expf(-ty));
  float px = sx * 480.f, py = sy * 1440.f;
#pragma unroll
  for (int c = 0; c < 7; ++c) {
    const float* M = proj + c*9;
    float icx = M[0]*px + M[1]*py + M[2];
    float icy = M[3]*px + M[4]*py + M[5];
    float icz = M[6]*px + M[7]*py + M[8];
    float zc = fmaxf(icz, 1e-5f);
    float cx = (icx/zc/1920.f - 0.5f) * 2.f;
    float cy = (icy/zc/1080.f - 0.5f) * 2.f;
    int ok = (icz > 1e-5f) && (cx > -1.f) && (cx < 1.f) && (cy > -1.f) && (cy < 1.f);
    camxy[((long long)c*3600+n)*2+0] = cx;
    camxy[((long long)c*3600+n)*2+1] = cy;
    valid[(long long)c*3600+n] = ok ? 1.f : 0.f;
  }
}

// bilinear grid sample, align_corners=False, zero padding.
// block = pt*7+cam, threads over 512 channels. writes x[pt][cam][c].
__global__ __launch_bounds__(256) void grid_sample_k(
    const float* __restrict__ feats, const float* __restrict__ camxy, float* __restrict__ xout)
{
  int blk = blockIdx.x;
  int pt = blk / 7, cam = blk % 7;
  float gx = camxy[((long long)cam*3600+pt)*2+0];
  float gy = camxy[((long long)cam*3600+pt)*2+1];
  float fx = (gx + 1.f) * 60.f - 0.5f;   // W=120
  float fy = (gy + 1.f) * 34.f - 0.5f;   // H=68
  float x0f = floorf(fx), y0f = floorf(fy);
  float wx1 = fx - x0f, wy1 = fy - y0f;
  float wx0 = 1.f - wx1, wy0 = 1.f - wy1;
  x0f = fminf(fmaxf(x0f, -2.e9f), 2.e9f);
  y0f = fminf(fmaxf(y0f, -2.e9f), 2.e9f);
  int x0 = (int)x0f, y0 = (int)y0f;
  int x1 = x0 + 1, y1 = y0 + 1;
  bool okx0 = (x0 >= 0) && (x0 < 120);
  bool okx1 = (x1 >= 0) && (x1 < 120);
  bool oky0 = (y0 >= 0) && (y0 < 68);
  bool oky1 = (y1 >= 0) && (y1 < 68);
  int cx0 = min(max(x0,0),119), cx1 = min(max(x1,0),119);
  int cy0 = min(max(y0,0),67),  cy1 = min(max(y1,0),67);
  float w00 = (okx0 && oky0) ? wy0*wx0 : 0.f;
  float w01 = (okx1 && oky0) ? wy0*wx1 : 0.f;
  float w10 = (okx0 && oky1) ? wy1*wx0 : 0.f;
  float w11 = (okx1 && oky1) ? wy1*wx1 : 0.f;
  int i00 = cy0*120+cx0, i01 = cy0*120+cx1, i10 = cy1*120+cx0, i11 = cy1*120+cx1;
  const float* f = feats + (long long)cam * 512 * 8160;
  float* o = xout + (long long)blk * 512;
  for (int c = threadIdx.x; c < 512; c += 256) {
    const float* fc = f + (long long)c * 8160;
    o[c] = fc[i00]*w00 + fc[i01]*w01 + fc[i10]*w10 + fc[i11]*w11;
  }
}

// Per-batch 7-token MHA (nh=8, d=64) with the reference's (preserved-bug) mask.
// qkv holds this chunk's rows [lb*7 .. lb*7+7) x 1536. out rows are GLOBAL.
__global__ __launch_bounds__(256) void tf_attn_k(
    const float* __restrict__ qkv, const float* __restrict__ valid,
    float* __restrict__ outp, int batch0)
{
  __shared__ float sv[7*1536];
  const int lb = blockIdx.x;
  const int ib = batch0 + lb;
  const float4* src = (const float4*)(qkv + (long long)lb * (7*1536));
  float4* dst4 = (float4*)sv;
  for (int idx = threadIdx.x; idx < 7*1536/4; idx += 256) dst4[idx] = src[idx];
  __syncthreads();
  const int tid = threadIdx.x;
  if (tid < 56) {
    const int h = tid / 7, sq = tid % 7;
    const int bb = ib*8 + h;
    const int pp = bb / 7200;
    const int rr = (bb - pp*7200) % 900;
    const float* qrow = sv + sq*1536 + h*64;
    float sc[7];
    float mx = -3.0e38f;
#pragma unroll
    for (int t = 0; t < 7; ++t) {
      const float* krow = sv + t*1536 + 512 + h*64;
      float d = 0.f;
      for (int e = 0; e < 64; ++e) d = fmaf(qrow[e], krow[e], d);
      d *= 0.125f;
      if (valid[(long long)t*3600 + rr*4 + pp] == 0.f) d = -1e9f;
      sc[t] = d;
      mx = fmaxf(mx, d);
    }
    float sum = 0.f;
#pragma unroll
    for (int t = 0; t < 7; ++t) { sc[t] = expf(sc[t] - mx); sum += sc[t]; }
    float inv = 1.f / sum;
#pragma unroll
    for (int t = 0; t < 7; ++t) sc[t] *= inv;
    float* orow = outp + ((long long)ib*7 + sq)*512 + h*64;
    for (int e = 0; e < 64; e += 4) {
      float a0=0.f, a1=0.f, a2=0.f, a3=0.f;
#pragma unroll
      for (int t = 0; t < 7; ++t) {
        const float* vr = sv + t*1536 + 1024 + h*64 + e;
        float w = sc[t];
        a0 = fmaf(w, vr[0], a0); a1 = fmaf(w, vr[1], a1);
        a2 = fmaf(w, vr[2], a2); a3 = fmaf(w, vr[3], a3);
      }
      float4 v4 = make_float4(a0, a1, a2, a3);
      *(float4*)(orow + e) = v4;
    }
  }
}

// pooled[q,c] = (1/28) * sum_p aw[q,p] * sum_cam x[(q*4+p),cam,c]
__global__ __launch_bounds__(256) void pool_k(
    const float* __restrict__ x, const float* __restrict__ aw, float* __restrict__ o)
{
  int qq = blockIdx.x;
  for (int c = threadIdx.x; c < 512; c += 256) {
    float acc = 0.f;
#pragma unroll
    for (int p = 0; p < 4; ++p) {
      const float* xr = x + ((long long)(qq*4+p)*7)*512 + c;
      float s = 0.f;
#pragma unroll
      for (int cam = 0; cam < 7; ++cam) s += xr[cam*512];
      acc = fmaf(s, aw[qq*4+p], acc);
    }
    o[(long long)qq*512 + c] = acc * (1.f/28.f);
  }
}

// pe1[q,c] = invsig(ref[q,0])*w1[c,0] + invsig(ref[q,1])*w1[c,1] + b1[c]
__global__ __launch_bounds__(256) void pe1_k(
    const float* __restrict__ ref, const float* __restrict__ w1, const float* __restrict__ b1,
    float* __restrict__ o)
{
  int idx = blockIdx.x * 256 + threadIdx.x;
  if (idx >= 900*512) return;
  int qq = idx >> 9, c = idx & 511;
  float i0 = inv_sig(ref[qq*2+0]);
  float i1 = inv_sig(ref[qq*2+1]);
  o[idx] = i0*w1[c*2+0] + i1*w1[c*2+1] + b1[c];
}

// ============================================================================
extern "C" void kernel_launch(void* const* d_in, const int* in_sizes, int n_in,
                              void* d_out, int out_size, void* d_ws, size_t ws_size,
                              hipStream_t stream)
{
  (void)in_sizes; (void)n_in; (void)out_size;
  const float* img      = (const float*)d_in[0];
  const float* proj     = (const float*)d_in[1];
  const float* query    = (const float*)d_in[2];
  const float* qpos     = (const float*)d_in[3];
  const float* ref      = (const float*)d_in[4];
  const float* mha_in_w = (const float*)d_in[5];
  const float* mha_in_b = (const float*)d_in[6];
  const float* mha_out_w= (const float*)d_in[7];
  const float* mha_out_b= (const float*)d_in[8];
  const float* off_w1   = (const float*)d_in[9];
  const float* off_b1   = (const float*)d_in[10];
  const float* off_w2   = (const float*)d_in[11];
  const float* off_b2   = (const float*)d_in[12];
  const float* am_w1    = (const float*)d_in[13];
  const float* am_b1    = (const float*)d_in[14];
  const float* am_w2    = (const float*)d_in[15];
  const float* am_b2    = (const float*)d_in[16];
  const float* t_ln1_g  = (const float*)d_in[17];
  const float* t_ln1_b  = (const float*)d_in[18];
  const float* t_in_w   = (const float*)d_in[19];
  const float* t_in_b   = (const float*)d_in[20];
  const float* t_out_w  = (const float*)d_in[21];
  const float* t_out_b  = (const float*)d_in[22];
  const float* t_ln2_g  = (const float*)d_in[23];
  const float* t_ln2_b  = (const float*)d_in[24];
  const float* t_ff_w1  = (const float*)d_in[25];
  const float* t_ff_b1  = (const float*)d_in[26];
  const float* t_ff_w2  = (const float*)d_in[27];
  const float* t_ff_b2  = (const float*)d_in[28];
  const float* ffn_w1   = (const float*)d_in[29];
  const float* ffn_b1   = (const float*)d_in[30];
  const float* ffn_w2   = (const float*)d_in[31];
  const float* ffn_b2   = (const float*)d_in[32];
  const float* op_w     = (const float*)d_in[33];
  const float* op_b     = (const float*)d_in[34];
  const float* pe_w1    = (const float*)d_in[35];
  const float* pe_bias1 = (const float*)d_in[36];
  const float* pe_ln1_g = (const float*)d_in[37];
  const float* pe_ln1_b = (const float*)d_in[38];
  const float* pe_w2    = (const float*)d_in[39];
  const float* pe_bias2 = (const float*)d_in[40];
  const float* pe_ln2_g = (const float*)d_in[41];
  const float* pe_ln2_b = (const float*)d_in[42];
  const float* ln1_g    = (const float*)d_in[43];
  const float* ln1_b    = (const float*)d_in[44];
  const float* ln2_g    = (const float*)d_in[45];
  const float* ln2_b    = (const float*)d_in[46];
  const float* ln3_g    = (const float*)d_in[47];
  const float* ln3_b    = (const float*)d_in[48];

  char* wsb = (char*)d_ws;
  size_t off = 0;
  auto alloc = [&](long long elems) -> float* {
    float* p = (float*)(wsb + off);
    off += (size_t)(((elems * 4) + 255) / 256 * 256);
    return p;
  };
  float* X    = alloc(25200ll * 512);   // token tensor [3600,7,512]
  float* XN   = alloc(25200ll * 512);   // LN'd tokens / attn out
  float* QKV  = alloc(8400ll * 1536);   // chunk qkv / stage1 scratch / ff hidden
  float* S0   = alloc(900ll * 512);
  float* S1   = alloc(900ll * 512);
  float* S2   = alloc(900ll * 512);
  float* S3   = alloc(900ll * 512);
  float* S4   = alloc(900ll * 512);
  float* S5   = alloc(900ll * 512);
  float* OFFB = alloc(900ll * 8);
  float* AMB  = alloc(900ll * 4);
  float* CXY  = alloc(7ll * 3600 * 2);
  float* VAL  = alloc(7ll * 3600);
  if (off > ws_size) return;  // workspace too small -> fail visibly

  float* SC = QKV + 1382400;  // stage-1 scores [8,900,900] after qkv1 [900,1536]

  auto gemm = [&](const float* A, long long ab, int ars, int acs, long long azs,
                  const float* W, long long wb, int wrs, int wcs, long long wzs,
                  const float* bias, const float* R, int rrs, long long rzs,
                  float* C, long long cb, int crs, long long czs,
                  int M, int N, int K, float alpha, int flags, int Z) {
    dim3 grd((unsigned)((N + 127) / 128), (unsigned)((M + 127) / 128), (unsigned)Z);
    gemm_k<<<grd, dim3(256), 0, stream>>>(A, ab, ars, acs, azs, W, wb, wrs, wcs, wzs,
                                          bias, R, rrs, rzs, C, cb, crs, czs,
                                          M, N, K, alpha, flags);
  };

  // ---------------- stage 1: self-attention over queries ----------------
  add2_k<<<1800, 256, 0, stream>>>(query, qpos, S0, 460800);                 // q
  gemm(S0,0,512,1,0,  mha_in_w,0,512,1,0,  mha_in_b, nullptr,0,0,
       QKV,0,1536,0,  900,1536,512, 1.f, 1, 1);                              // qkv1
  gemm(QKV,0,1536,1,64,  QKV,512,1536,1,64,  nullptr, nullptr,0,0,
       SC,0,900,810000,  900,900,64, 0.125f, 0, 8);                          // scores
  softmax_k<<<7200, 256, 0, stream>>>(SC, 900);
  gemm(SC,0,900,1,810000,  QKV,1024,1,1536,64,  nullptr, nullptr,0,0,
       S1,0,512,64,  900,64,900, 1.f, 0, 8);                                 // o
  gemm(S1,0,512,1,0,  mha_out_w,0,512,1,0,  mha_out_b, S0,512,0,
       S2,0,512,0,  900,512,512, 1.f, 1|4, 1);                               // a_out+q
  ln_k<<<900, 256, 0, stream>>>(S2, nullptr, nullptr, ln1_g, ln1_b, S1, 0);  // qn=S1

  gemm(S1,0,512,1,0, off_w1,0,512,1,0, off_b1, nullptr,0,0,
       S2,0,512,0, 900,512,512, 1.f, 1|2, 1);
  gemm(S2,0,512,1,0, off_w2,0,512,1,0, off_b2, nullptr,0,0,
       OFFB,0,8,0, 900,8,512, 1.f, 1, 1);                                    // offsets
  gemm(S1,0,512,1,0, am_w1,0,512,1,0, am_b1, nullptr,0,0,
       S2,0,512,0, 900,512,512, 1.f, 1|2, 1);
  gemm(S2,0,512,1,0, am_w2,0,512,1,0, am_b2, nullptr,0,0,
       AMB,0,4,0, 900,4,512, 1.f, 1, 1);                                     // am logits
  softmax4_k<<<4, 256, 0, stream>>>(AMB, 900);                               // attn_w

  sample_prep_k<<<15, 256, 0, stream>>>(ref, OFFB, proj, CXY, VAL);
  grid_sample_k<<<25200, 256, 0, stream>>>(img, CXY, X);                     // x tokens

  // ---------------- transformer, depth 4 ----------------
  for (int L = 0; L < 4; ++L) {
    const float* g1  = t_ln1_g + L*512;  const float* bb1 = t_ln1_b + L*512;
    const float* wq  = t_in_w  + (long long)L*1536*512; const float* bq = t_in_b + L*1536;
    const float* wo  = t_out_w + (long long)L*512*512;  const float* bo = t_out_b + L*512;
    const float* g2  = t_ln2_g + L*512;  const float* bb2 = t_ln2_b + L*512;
    const float* w1  = t_ff_w1 + (long long)L*512*512;  const float* f1 = t_ff_b1 + L*512;
    const float* w2  = t_ff_w2 + (long long)L*512*512;  const float* f2 = t_ff_b2 + L*512;

    ln_k<<<25200, 256, 0, stream>>>(X, nullptr, nullptr, g1, bb1, XN, 0);
    for (int ch = 0; ch < 3; ++ch) {
      long long row0 = (long long)ch * 8400;
      gemm(XN, row0*512, 512, 1, 0,  wq, 0, 512, 1, 0,  bq, nullptr, 0, 0,
           QKV, 0, 1536, 0,  8400, 1536, 512, 1.f, 1, 1);
      tf_attn_k<<<1200, 256, 0, stream>>>(QKV, VAL, XN, ch*1200);
    }
    gemm(XN,0,512,1,0,  wo,0,512,1,0,  bo, X,512,0,
         X,0,512,0,  25200,512,512, 1.f, 1|4, 1);                            // attn+res
    ln_k<<<25200, 256, 0, stream>>>(X, nullptr, nullptr, g2, bb2, XN, 0);
    gemm(XN,0,512,1,0,  w1,0,512,1,0,  f1, nullptr,0,0,
         QKV,0,512,0,  25200,512,512, 1.f, 1|2, 1);                          // ff hidden
    gemm(QKV,0,512,1,0,  w2,0,512,1,0,  f2, X,512,0,
         X,0,512,0,  25200,512,512, 1.f, 1|4, 1);                            // ff+res
  }

  // ---------------- tail ----------------
  pool_k<<<900, 256, 0, stream>>>(X, AMB, S3);                               // pooled
  gemm(S3,0,512,1,0, op_w,0,512,1,0, op_b, nullptr,0,0,
       S4,0,512,0, 900,512,512, 1.f, 1, 1);                                  // out=S4
  pe1_k<<<1800, 256, 0, stream>>>(ref, pe_w1, pe_bias1, S2);
  ln_k<<<900, 256, 0, stream>>>(S2, nullptr, nullptr, pe_ln1_g, pe_ln1_b, S5, 1);
  gemm(S5,0,512,1,0, pe_w2,0,512,1,0, pe_bias2, nullptr,0,0,
       S2,0,512,0, 900,512,512, 1.f, 1, 1);
  ln_k<<<900, 256, 0, stream>>>(S2, nullptr, nullptr, pe_ln2_g, pe_ln2_b, S5, 1); // pe=S5
  ln_k<<<900, 256, 0, stream>>>(S4, S1, S5, ln2_g, ln2_b, S3, 0);            // qf=S3
  gemm(S3,0,512,1,0, ffn_w1,0,512,1,0, ffn_b1, nullptr,0,0,
       S2,0,512,0, 900,512,512, 1.f, 1|2, 1);
  gemm(S2,0,512,1,0, ffn_w2,0,512,1,0, ffn_b2, S3,512,0,
       S4,0,512,0, 900,512,512, 1.f, 1|4, 1);
  ln_k<<<900, 256, 0, stream>>>(S4, nullptr, nullptr, ln3_g, ln3_b, (float*)d_out, 0);
}

// Round 3
// 3920.629 us; speedup vs baseline: 2.2156x; 2.2156x over previous
//
#include <hip/hip_runtime.h>
#include <hip/hip_bf16.h>

#define DEVI __device__ __forceinline__

typedef __bf16 bf16x8 __attribute__((ext_vector_type(8)));
typedef float f32x4 __attribute__((ext_vector_type(4)));

#define GLDS(gp, lp) __builtin_amdgcn_global_load_lds( \
    (const __attribute__((address_space(1))) void*)(gp), \
    (__attribute__((address_space(3))) void*)(lp), 16, 0, 0)

DEVI float b2f(ushort u) { unsigned v = ((unsigned)u) << 16; return __builtin_bit_cast(float, v); }
DEVI ushort f2bu(float x) { __hip_bfloat16 h = __float2bfloat16(x); return __builtin_bit_cast(ushort, h); }

// ============================================================================
// bf16 MFMA GEMM: C[m,n] = sum_k A[m,k]*W[n,k]  (+bias)(relu)(+R), K mult of 32,
// N mult of 128, A rows padded so reads up to ceil(M/128)*128 are in-bounds.
// flags: 1=bias, 2=relu, 4=residual(fp32 R, ld=N), 8=write bf16 Cb instead of Cf
// 128x128 tile, BK=32, 256 thr = 4 waves (2x2 of 64x64), 16x16x32 MFMA.
// LDS slot-swizzle: slot' = slot ^ (row&3), applied on global src + LDS read.
// ============================================================================
__global__ __launch_bounds__(256) void gemm_mfma_k(
    const ushort* __restrict__ Ah, const ushort* __restrict__ Wh,
    const float* __restrict__ bias, const float* Rp,
    float* Cf, ushort* Cb,
    int M, int N, int K, int flags)
{
  __shared__ ushort As[128 * 32];
  __shared__ ushort Bs[128 * 32];
  const int tid = threadIdx.x;
  const int lane = tid & 63;
  const int wid = tid >> 6;
  const int bn = blockIdx.x * 128;
  const int bm = blockIdx.y * 128;
  const int wr = wid >> 1, wc = wid & 1;
  const int col = lane & 15;
  const int ksl = lane >> 4;
  const int sr = lane >> 2;     // staging row within 16-row issue
  const int sd = lane & 3;      // staging dest slot

  f32x4 acc[4][4];
#pragma unroll
  for (int m = 0; m < 4; ++m)
#pragma unroll
    for (int n = 0; n < 4; ++n) acc[m][n] = (f32x4){0.f, 0.f, 0.f, 0.f};

  for (int k0 = 0; k0 < K; k0 += 32) {
#pragma unroll
    for (int j = 0; j < 2; ++j) {
      const int r = wid * 32 + j * 16 + sr;
      const int ss = sd ^ (r & 3);
      GLDS(Ah + (long long)(bm + r) * K + k0 + ss * 8, &As[(wid * 32 + j * 16) * 32]);
      GLDS(Wh + (long long)(bn + r) * K + k0 + ss * 8, &Bs[(wid * 32 + j * 16) * 32]);
    }
    __syncthreads();
    bf16x8 af[4], bf[4];
#pragma unroll
    for (int m = 0; m < 4; ++m) {
      const int r = wr * 64 + m * 16 + col;
      af[m] = *(const bf16x8*)&As[r * 32 + ((ksl ^ (r & 3)) << 3)];
    }
#pragma unroll
    for (int n = 0; n < 4; ++n) {
      const int r = wc * 64 + n * 16 + col;
      bf[n] = *(const bf16x8*)&Bs[r * 32 + ((ksl ^ (r & 3)) << 3)];
    }
#pragma unroll
    for (int m = 0; m < 4; ++m)
#pragma unroll
      for (int n = 0; n < 4; ++n)
        acc[m][n] = __builtin_amdgcn_mfma_f32_16x16x32_bf16(af[m], bf[n], acc[m][n], 0, 0, 0);
    __syncthreads();
  }

  const int r4 = (lane >> 4) * 4;
#pragma unroll
  for (int m = 0; m < 4; ++m) {
#pragma unroll
    for (int j = 0; j < 4; ++j) {
      const int row = bm + wr * 64 + m * 16 + r4 + j;
      if (row >= M) continue;
#pragma unroll
      for (int n = 0; n < 4; ++n) {
        const int cn = bn + wc * 64 + n * 16 + col;
        float v = acc[m][n][j];
        if (flags & 1) v += bias[cn];
        if (flags & 2) v = fmaxf(v, 0.f);
        if (flags & 4) v += Rp[(long long)row * N + cn];
        if (flags & 8) Cb[(long long)row * N + cn] = f2bu(v);
        else           Cf[(long long)row * N + cn] = v;
      }
    }
  }
}

// ============================================================================
// Generic strided fp32 SGEMM (stage-1 / tail sizes only).
// flags: 1=bias, 2=relu, 4=residual
// ============================================================================
__global__ __launch_bounds__(256) void gemm_k(
    const float* __restrict__ Ap, long long a_base, int a_rs, int a_cs, long long a_zs,
    const float* __restrict__ Wp, long long w_base, int w_rs, int w_cs, long long w_zs,
    const float* __restrict__ bias,
    const float* Rp, int r_rs, long long r_zs,
    float* Cp, long long c_base, int c_rs, long long c_zs,
    int M, int N, int K, float alpha, int flags)
{
  __shared__ float As[8][132];
  __shared__ float Bs[8][132];
  const int z = blockIdx.z;
  const float* A = Ap + a_base + (long long)z * a_zs;
  const float* W = Wp + w_base + (long long)z * w_zs;
  float* C = Cp + c_base + (long long)z * c_zs;
  const float* R = (flags & 4) ? (Rp + (long long)z * r_zs) : nullptr;

  const int bm = blockIdx.y * 128;
  const int bn = blockIdx.x * 128;
  const int tid = threadIdx.x;
  const int tx = tid & 15;
  const int ty = tid >> 4;
  const int srow = tid >> 1;
  const int k4 = (tid & 1) * 4;

  float acc[8][8];
#pragma unroll
  for (int i = 0; i < 8; ++i)
#pragma unroll
    for (int j = 0; j < 8; ++j) acc[i][j] = 0.f;

  const int am = bm + srow;
  const int wn = bn + srow;
  const bool am_ok = am < M;
  const bool wn_ok = wn < N;
  const long long aoff = (long long)(am_ok ? am : 0) * a_rs;
  const long long woff = (long long)(wn_ok ? wn : 0) * w_rs;

  for (int k0 = 0; k0 < K; k0 += 8) {
    if (a_cs == 1 && am_ok && (k0 + 8 <= K)) {
      float4 v = *(const float4*)(A + aoff + k0 + k4);
      As[k4+0][srow] = v.x; As[k4+1][srow] = v.y;
      As[k4+2][srow] = v.z; As[k4+3][srow] = v.w;
    } else {
#pragma unroll
      for (int j = 0; j < 4; ++j) {
        int kk = k0 + k4 + j;
        float va = 0.f;
        if (am_ok && kk < K) va = A[aoff + (long long)kk * a_cs];
        As[k4+j][srow] = va;
      }
    }
    if (w_cs == 1 && wn_ok && (k0 + 8 <= K)) {
      float4 v = *(const float4*)(W + woff + k0 + k4);
      Bs[k4+0][srow] = v.x; Bs[k4+1][srow] = v.y;
      Bs[k4+2][srow] = v.z; Bs[k4+3][srow] = v.w;
    } else {
#pragma unroll
      for (int j = 0; j < 4; ++j) {
        int kk = k0 + k4 + j;
        float vb = 0.f;
        if (wn_ok && kk < K) vb = W[woff + (long long)kk * w_cs];
        Bs[k4+j][srow] = vb;
      }
    }
    __syncthreads();
#pragma unroll
    for (int kk = 0; kk < 8; ++kk) {
      float af[8], bf[8];
      *(float4*)&af[0] = *(const float4*)&As[kk][ty*8];
      *(float4*)&af[4] = *(const float4*)&As[kk][ty*8+4];
      *(float4*)&bf[0] = *(const float4*)&Bs[kk][tx*4];
      *(float4*)&bf[4] = *(const float4*)&Bs[kk][64+tx*4];
#pragma unroll
      for (int i = 0; i < 8; ++i)
#pragma unroll
        for (int j = 0; j < 8; ++j)
          acc[i][j] = fmaf(af[i], bf[j], acc[i][j]);
    }
    __syncthreads();
  }

#pragma unroll
  for (int i = 0; i < 8; ++i) {
    int m = bm + ty*8 + i;
    if (m >= M) continue;
#pragma unroll
    for (int jg = 0; jg < 2; ++jg) {
#pragma unroll
      for (int j = 0; j < 4; ++j) {
        int n = bn + jg*64 + tx*4 + j;
        if (n >= N) continue;
        float v = acc[i][jg*4+j] * alpha;
        if (flags & 1) v += bias[n];
        if (flags & 2) v = fmaxf(v, 0.f);
        if (flags & 4) v += R[(long long)m * r_rs + n];
        C[(long long)m * c_rs + n] = v;
      }
    }
  }
}

// ============================================================================
// LayerNorm over E=512; fused add of up to 2 extras; optional relu;
// writes bf16 to outb if non-null, else fp32 to outp.
// ============================================================================
__global__ __launch_bounds__(256) void ln_k(
    const float* __restrict__ in0, const float* __restrict__ in1, const float* __restrict__ in2,
    const float* __restrict__ g, const float* __restrict__ b,
    float* __restrict__ outp, ushort* __restrict__ outb, int relu)
{
  __shared__ float red[8];
  const long long base = (long long)blockIdx.x * 512;
  const int tid = threadIdx.x;
  float x0 = in0[base + tid];
  float x1 = in0[base + tid + 256];
  if (in1) { x0 += in1[base + tid]; x1 += in1[base + tid + 256]; }
  if (in2) { x0 += in2[base + tid]; x1 += in2[base + tid + 256]; }
  float s = x0 + x1, q = x0*x0 + x1*x1;
#pragma unroll
  for (int off = 32; off > 0; off >>= 1) {
    s += __shfl_down(s, off, 64);
    q += __shfl_down(q, off, 64);
  }
  if ((tid & 63) == 0) { red[tid >> 6] = s; red[4 + (tid >> 6)] = q; }
  __syncthreads();
  if (tid == 0) {
    float S = red[0]+red[1]+red[2]+red[3];
    float Q = red[4]+red[5]+red[6]+red[7];
    float m = S * (1.f/512.f);
    float v = Q * (1.f/512.f) - m*m;
    red[0] = m; red[1] = rsqrtf(v + 1e-5f);
  }
  __syncthreads();
  float m = red[0], inv = red[1];
  float y0 = (x0 - m) * inv * g[tid]     + b[tid];
  float y1 = (x1 - m) * inv * g[tid+256] + b[tid+256];
  if (relu) { y0 = fmaxf(y0, 0.f); y1 = fmaxf(y1, 0.f); }
  if (outb) {
    outb[base + tid]       = f2bu(y0);
    outb[base + tid + 256] = f2bu(y1);
  } else {
    outp[base + tid]       = y0;
    outp[base + tid + 256] = y1;
  }
}

__global__ __launch_bounds__(256) void softmax_k(float* __restrict__ p, int S)
{
  __shared__ float red[8];
  float* r = p + (long long)blockIdx.x * S;
  const int tid = threadIdx.x;
  float vals[4];
  int cnt = 0;
  float mx = -3.0e38f;
  for (int e = tid; e < S; e += 256) { float v = r[e]; vals[cnt++] = v; mx = fmaxf(mx, v); }
#pragma unroll
  for (int off = 32; off > 0; off >>= 1) mx = fmaxf(mx, __shfl_down(mx, off, 64));
  if ((tid & 63) == 0) red[tid >> 6] = mx;
  __syncthreads();
  if (tid == 0) red[0] = fmaxf(fmaxf(red[0], red[1]), fmaxf(red[2], red[3]));
  __syncthreads();
  mx = red[0];
  float sum = 0.f;
  for (int i = 0; i < cnt; ++i) { vals[i] = expf(vals[i] - mx); sum += vals[i]; }
#pragma unroll
  for (int off = 32; off > 0; off >>= 1) sum += __shfl_down(sum, off, 64);
  if ((tid & 63) == 0) red[4 + (tid >> 6)] = sum;
  __syncthreads();
  if (tid == 0) red[4] = red[4]+red[5]+red[6]+red[7];
  __syncthreads();
  float inv = 1.f / red[4];
  cnt = 0;
  for (int e = tid; e < S; e += 256) r[e] = vals[cnt++] * inv;
}

__global__ __launch_bounds__(256) void softmax4_k(float* __restrict__ p, int rows)
{
  int i = blockIdx.x * 256 + threadIdx.x;
  if (i >= rows) return;
  float* r = p + (long long)i * 4;
  float m = fmaxf(fmaxf(r[0], r[1]), fmaxf(r[2], r[3]));
  float e0 = expf(r[0]-m), e1 = expf(r[1]-m), e2 = expf(r[2]-m), e3 = expf(r[3]-m);
  float inv = 1.f / (e0+e1+e2+e3);
  r[0] = e0*inv; r[1] = e1*inv; r[2] = e2*inv; r[3] = e3*inv;
}

__global__ __launch_bounds__(256) void add2_k(
    const float* __restrict__ a, const float* __restrict__ b, float* __restrict__ o, int n)
{
  int i = blockIdx.x * 256 + threadIdx.x;
  if (i < n) o[i] = a[i] + b[i];
}

__global__ __launch_bounds__(256) void f2b_k(
    const float* __restrict__ in, ushort* __restrict__ out, int n)
{
  int i = blockIdx.x * 256 + threadIdx.x;
  if (i < n) out[i] = f2bu(in[i]);
}

DEVI float inv_sig(float x)
{
  x = fminf(fmaxf(x, 0.f), 1.f);
  float a = fmaxf(x, 1e-5f);
  float c = fmaxf(1.f - x, 1e-5f);
  return logf(a / c);
}

__global__ __launch_bounds__(256) void sample_prep_k(
    const float* __restrict__ ref, const float* __restrict__ offs,
    const float* __restrict__ proj, float* __restrict__ camxy, float* __restrict__ valid)
{
  int n = blockIdx.x * 256 + threadIdx.x;
  if (n >= 3600) return;
  int qq = n >> 2, pp = n & 3;
  int rrow = n % 900;
  float tx = inv_sig(ref[rrow*2+0]) + offs[qq*8 + pp*2 + 0];
  float ty = inv_sig(ref[rrow*2+1]) + offs[qq*8 + pp*2 + 1];
  float sx = 1.f / (1.f + expf(-tx));
  float sy = 1.f / (1.f + expf(-ty));
  float px = sx * 480.f, py = sy * 1440.f;
#pragma unroll
  for (int c = 0; c < 7; ++c) {
    const float* M = proj + c*9;
    float icx = M[0]*px + M[1]*py + M[2];
    float icy = M[3]*px + M[4]*py + M[5];
    float icz = M[6]*px + M[7]*py + M[8];
    float zc = fmaxf(icz, 1e-5f);
    float cx = (icx/zc/1920.f - 0.5f) * 2.f;
    float cy = (icy/zc/1080.f - 0.5f) * 2.f;
    int ok = (icz > 1e-5f) && (cx > -1.f) && (cx < 1.f) && (cy > -1.f) && (cy < 1.f);
    camxy[((long long)c*3600+n)*2+0] = cx;
    camxy[((long long)c*3600+n)*2+1] = cy;
    valid[(long long)c*3600+n] = ok ? 1.f : 0.f;
  }
}

// img [7][512][8160] fp32 -> imgT [7][8160][512] bf16 (32x32 LDS tiles)
__global__ __launch_bounds__(256) void timg_k(
    const float* __restrict__ img, ushort* __restrict__ out)
{
  __shared__ float t[32][33];
  const int cam = blockIdx.z;
  const int hw0 = blockIdx.x * 32;
  const int c0  = blockIdx.y * 32;
  const int tx = threadIdx.x & 31, ty = threadIdx.x >> 5;
  const float* src = img + ((long long)cam * 512 + c0) * 8160 + hw0;
#pragma unroll
  for (int i = 0; i < 4; ++i)
    t[ty + i*8][tx] = src[(long long)(ty + i*8) * 8160 + tx];
  __syncthreads();
  ushort* dst = out + ((long long)cam * 8160 + hw0) * 512 + c0;
#pragma unroll
  for (int i = 0; i < 4; ++i)
    dst[(long long)(ty + i*8) * 512 + tx] = f2bu(t[tx][ty + i*8]);
}

// bilinear sample from channel-last bf16: block = pt*7+cam, 128 thr x 4 ch
__global__ __launch_bounds__(128) void grid_sample2_k(
    const ushort* __restrict__ imgT, const float* __restrict__ camxy,
    float* __restrict__ xout)
{
  const int blk = blockIdx.x;
  const int pt = blk / 7, cam = blk % 7;
  float gx = camxy[((long long)cam*3600+pt)*2+0];
  float gy = camxy[((long long)cam*3600+pt)*2+1];
  float fx = (gx + 1.f) * 60.f - 0.5f;   // W=120
  float fy = (gy + 1.f) * 34.f - 0.5f;   // H=68
  float x0f = floorf(fx), y0f = floorf(fy);
  float wx1 = fx - x0f, wy1 = fy - y0f;
  float wx0 = 1.f - wx1, wy0 = 1.f - wy1;
  x0f = fminf(fmaxf(x0f, -2.e9f), 2.e9f);
  y0f = fminf(fmaxf(y0f, -2.e9f), 2.e9f);
  int x0 = (int)x0f, y0 = (int)y0f;
  int x1 = x0 + 1, y1 = y0 + 1;
  bool okx0 = (x0 >= 0) && (x0 < 120);
  bool okx1 = (x1 >= 0) && (x1 < 120);
  bool oky0 = (y0 >= 0) && (y0 < 68);
  bool oky1 = (y1 >= 0) && (y1 < 68);
  int cx0 = min(max(x0,0),119), cx1 = min(max(x1,0),119);
  int cy0 = min(max(y0,0),67),  cy1 = min(max(y1,0),67);
  float w00 = (okx0 && oky0) ? wy0*wx0 : 0.f;
  float w01 = (okx1 && oky0) ? wy0*wx1 : 0.f;
  float w10 = (okx0 && oky1) ? wy1*wx0 : 0.f;
  float w11 = (okx1 && oky1) ? wy1*wx1 : 0.f;
  const long long i00 = (long long)(cy0*120+cx0) * 512;
  const long long i01 = (long long)(cy0*120+cx1) * 512;
  const long long i10 = (long long)(cy1*120+cx0) * 512;
  const long long i11 = (long long)(cy1*120+cx1) * 512;
  const ushort* f = imgT + (long long)cam * 8160 * 512;
  float* o = xout + (long long)blk * 512;
  const int c = threadIdx.x * 4;
  ushort4 u00 = *(const ushort4*)(f + i00 + c);
  ushort4 u01 = *(const ushort4*)(f + i01 + c);
  ushort4 u10 = *(const ushort4*)(f + i10 + c);
  ushort4 u11 = *(const ushort4*)(f + i11 + c);
  float4 r;
  r.x = b2f(u00.x)*w00 + b2f(u01.x)*w01 + b2f(u10.x)*w10 + b2f(u11.x)*w11;
  r.y = b2f(u00.y)*w00 + b2f(u01.y)*w01 + b2f(u10.y)*w10 + b2f(u11.y)*w11;
  r.z = b2f(u00.z)*w00 + b2f(u01.z)*w01 + b2f(u10.z)*w10 + b2f(u11.z)*w11;
  r.w = b2f(u00.w)*w00 + b2f(u01.w)*w01 + b2f(u10.w)*w10 + b2f(u11.w)*w11;
  *(float4*)(o + c) = r;
}

// Per-batch 7-token MHA; qkv = this chunk's rows fp32; out bf16 at GLOBAL rows.
__global__ __launch_bounds__(256) void tf_attn_k(
    const float* __restrict__ qkv, const float* __restrict__ valid,
    ushort* __restrict__ outp, int batch0)
{
  __shared__ float sv[7*1536];
  const int lb = blockIdx.x;
  const int ib = batch0 + lb;
  const float4* src = (const float4*)(qkv + (long long)lb * (7*1536));
  float4* dst4 = (float4*)sv;
  for (int idx = threadIdx.x; idx < 7*1536/4; idx += 256) dst4[idx] = src[idx];
  __syncthreads();
  const int tid = threadIdx.x;
  if (tid < 56) {
    const int h = tid / 7, sq = tid % 7;
    const int bb = ib*8 + h;
    const int pp = bb / 7200;
    const int rr = (bb - pp*7200) % 900;
    const float* qrow = sv + sq*1536 + h*64;
    float sc[7];
    float mx = -3.0e38f;
#pragma unroll
    for (int t = 0; t < 7; ++t) {
      const float* krow = sv + t*1536 + 512 + h*64;
      float d = 0.f;
      for (int e = 0; e < 64; ++e) d = fmaf(qrow[e], krow[e], d);
      d *= 0.125f;
      if (valid[(long long)t*3600 + rr*4 + pp] == 0.f) d = -1e9f;
      sc[t] = d;
      mx = fmaxf(mx, d);
    }
    float sum = 0.f;
#pragma unroll
    for (int t = 0; t < 7; ++t) { sc[t] = expf(sc[t] - mx); sum += sc[t]; }
    float inv = 1.f / sum;
#pragma unroll
    for (int t = 0; t < 7; ++t) sc[t] *= inv;
    ushort* orow = outp + ((long long)ib*7 + sq)*512 + h*64;
    for (int e = 0; e < 64; e += 4) {
      float a0=0.f, a1=0.f, a2=0.f, a3=0.f;
#pragma unroll
      for (int t = 0; t < 7; ++t) {
        const float* vr = sv + t*1536 + 1024 + h*64 + e;
        float w = sc[t];
        a0 = fmaf(w, vr[0], a0); a1 = fmaf(w, vr[1], a1);
        a2 = fmaf(w, vr[2], a2); a3 = fmaf(w, vr[3], a3);
      }
      ushort4 st;
      st.x = f2bu(a0); st.y = f2bu(a1); st.z = f2bu(a2); st.w = f2bu(a3);
      *(ushort4*)orow = st;
      orow += 4;
    }
  }
}

__global__ __launch_bounds__(256) void pool_k(
    const float* __restrict__ x, const float* __restrict__ aw, float* __restrict__ o)
{
  int qq = blockIdx.x;
  for (int c = threadIdx.x; c < 512; c += 256) {
    float acc = 0.f;
#pragma unroll
    for (int p = 0; p < 4; ++p) {
      const float* xr = x + ((long long)(qq*4+p)*7)*512 + c;
      float s = 0.f;
#pragma unroll
      for (int cam = 0; cam < 7; ++cam) s += xr[cam*512];
      acc = fmaf(s, aw[qq*4+p], acc);
    }
    o[(long long)qq*512 + c] = acc * (1.f/28.f);
  }
}

__global__ __launch_bounds__(256) void pe1_k(
    const float* __restrict__ ref, const float* __restrict__ w1, const float* __restrict__ b1,
    float* __restrict__ o)
{
  int idx = blockIdx.x * 256 + threadIdx.x;
  if (idx >= 900*512) return;
  int qq = idx >> 9, c = idx & 511;
  float i0 = inv_sig(ref[qq*2+0]);
  float i1 = inv_sig(ref[qq*2+1]);
  o[idx] = i0*w1[c*2+0] + i1*w1[c*2+1] + b1[c];
}

// ============================================================================
extern "C" void kernel_launch(void* const* d_in, const int* in_sizes, int n_in,
                              void* d_out, int out_size, void* d_ws, size_t ws_size,
                              hipStream_t stream)
{
  (void)in_sizes; (void)n_in; (void)out_size;
  const float* img      = (const float*)d_in[0];
  const float* proj     = (const float*)d_in[1];
  const float* query    = (const float*)d_in[2];
  const float* qpos     = (const float*)d_in[3];
  const float* ref      = (const float*)d_in[4];
  const float* mha_in_w = (const float*)d_in[5];
  const float* mha_in_b = (const float*)d_in[6];
  const float* mha_out_w= (const float*)d_in[7];
  const float* mha_out_b= (const float*)d_in[8];
  const float* off_w1   = (const float*)d_in[9];
  const float* off_b1   = (const float*)d_in[10];
  const float* off_w2   = (const float*)d_in[11];
  const float* off_b2   = (const float*)d_in[12];
  const float* am_w1    = (const float*)d_in[13];
  const float* am_b1    = (const float*)d_in[14];
  const float* am_w2    = (const float*)d_in[15];
  const float* am_b2    = (const float*)d_in[16];
  const float* t_ln1_g  = (const float*)d_in[17];
  const float* t_ln1_b  = (const float*)d_in[18];
  const float* t_in_w   = (const float*)d_in[19];
  const float* t_in_b   = (const float*)d_in[20];
  const float* t_out_w  = (const float*)d_in[21];
  const float* t_out_b  = (const float*)d_in[22];
  const float* t_ln2_g  = (const float*)d_in[23];
  const float* t_ln2_b  = (const float*)d_in[24];
  const float* t_ff_w1  = (const float*)d_in[25];
  const float* t_ff_b1  = (const float*)d_in[26];
  const float* t_ff_w2  = (const float*)d_in[27];
  const float* t_ff_b2  = (const float*)d_in[28];
  const float* ffn_w1   = (const float*)d_in[29];
  const float* ffn_b1   = (const float*)d_in[30];
  const float* ffn_w2   = (const float*)d_in[31];
  const float* ffn_b2   = (const float*)d_in[32];
  const float* op_w     = (const float*)d_in[33];
  const float* op_b     = (const float*)d_in[34];
  const float* pe_w1    = (const float*)d_in[35];
  const float* pe_bias1 = (const float*)d_in[36];
  const float* pe_ln1_g = (const float*)d_in[37];
  const float* pe_ln1_b = (const float*)d_in[38];
  const float* pe_w2    = (const float*)d_in[39];
  const float* pe_bias2 = (const float*)d_in[40];
  const float* pe_ln2_g = (const float*)d_in[41];
  const float* pe_ln2_b = (const float*)d_in[42];
  const float* ln1_g    = (const float*)d_in[43];
  const float* ln1_b    = (const float*)d_in[44];
  const float* ln2_g    = (const float*)d_in[45];
  const float* ln2_b    = (const float*)d_in[46];
  const float* ln3_g    = (const float*)d_in[47];
  const float* ln3_b    = (const float*)d_in[48];

  char* wsb = (char*)d_ws;
  size_t off = 0;
  auto alloc = [&](long long bytes) -> char* {
    char* p = wsb + off;
    off += (size_t)((bytes + 255) / 256 * 256);
    return p;
  };
  float* X    = (float*)alloc(25200ll * 512 * 4);      // tokens [3600*7][512]; SC overlays pre-sample
  float* QKV  = (float*)alloc(4200ll * 1536 * 4);      // per-chunk qkv fp32; qkv1 overlay
  char*  R1   = alloc(7ll * 8160 * 512 * 2);           // imgT bf16, later XNh+Hh
  ushort* imgT = (ushort*)R1;
  ushort* XNh  = (ushort*)R1;                          // [25344][512]
  ushort* Hh   = (ushort*)(R1 + 25344ll * 512 * 2);    // [25344][512]
  ushort* Wqkvh = (ushort*)alloc(4ll * 1536 * 512 * 2);
  ushort* Wouth = (ushort*)alloc(4ll * 512 * 512 * 2);
  ushort* Wff1h = (ushort*)alloc(4ll * 512 * 512 * 2);
  ushort* Wff2h = (ushort*)alloc(4ll * 512 * 512 * 2);
  float* S0   = (float*)alloc(900ll * 512 * 4);
  float* S1   = (float*)alloc(900ll * 512 * 4);
  float* S2   = (float*)alloc(900ll * 512 * 4);
  float* S3   = (float*)alloc(900ll * 512 * 4);
  float* S4   = (float*)alloc(900ll * 512 * 4);
  float* S5   = (float*)alloc(900ll * 512 * 4);
  float* OFFB = (float*)alloc(900ll * 8 * 4);
  float* AMB  = (float*)alloc(900ll * 4 * 4);
  float* CXY  = (float*)alloc(7ll * 3600 * 2 * 4);
  float* VAL  = (float*)alloc(7ll * 3600 * 4);
  if (off > ws_size) return;

  float* SC = X;              // stage-1 scores [8][900][900] (dead before sampling)
  float* QKV1 = QKV;          // stage-1 qkv [900][1536]

  auto gemm = [&](const float* A, long long ab, int ars, int acs, long long azs,
                  const float* W, long long wb, int wrs, int wcs, long long wzs,
                  const float* bias, const float* R, int rrs, long long rzs,
                  float* C, long long cb, int crs, long long czs,
                  int M, int N, int K, float alpha, int flags, int Z) {
    dim3 grd((unsigned)((N + 127) / 128), (unsigned)((M + 127) / 128), (unsigned)Z);
    gemm_k<<<grd, dim3(256), 0, stream>>>(A, ab, ars, acs, azs, W, wb, wrs, wcs, wzs,
                                          bias, R, rrs, rzs, C, cb, crs, czs,
                                          M, N, K, alpha, flags);
  };
  auto mgemm = [&](const ushort* A, const ushort* W, const float* bias,
                   const float* R, float* Cf, ushort* Cb,
                   int M, int N, int K, int flags) {
    dim3 grd((unsigned)(N / 128), (unsigned)((M + 127) / 128), 1);
    gemm_mfma_k<<<grd, dim3(256), 0, stream>>>(A, W, bias, R, Cf, Cb, M, N, K, flags);
  };

  // weight conversion (every launch; ws is re-poisoned)
  f2b_k<<<(4*1536*512+255)/256, 256, 0, stream>>>(t_in_w,  Wqkvh, 4*1536*512);
  f2b_k<<<(4*512*512+255)/256, 256, 0, stream>>>(t_out_w, Wouth, 4*512*512);
  f2b_k<<<(4*512*512+255)/256, 256, 0, stream>>>(t_ff_w1, Wff1h, 4*512*512);
  f2b_k<<<(4*512*512+255)/256, 256, 0, stream>>>(t_ff_w2, Wff2h, 4*512*512);
  // img transpose to channel-last bf16
  timg_k<<<dim3(255, 16, 7), 256, 0, stream>>>(img, imgT);

  // ---------------- stage 1: self-attention over queries (fp32) --------------
  add2_k<<<1800, 256, 0, stream>>>(query, qpos, S0, 460800);
  gemm(S0,0,512,1,0,  mha_in_w,0,512,1,0,  mha_in_b, nullptr,0,0,
       QKV1,0,1536,0,  900,1536,512, 1.f, 1, 1);
  gemm(QKV1,0,1536,1,64,  QKV1,512,1536,1,64,  nullptr, nullptr,0,0,
       SC,0,900,810000,  900,900,64, 0.125f, 0, 8);
  softmax_k<<<7200, 256, 0, stream>>>(SC, 900);
  gemm(SC,0,900,1,810000,  QKV1,1024,1,1536,64,  nullptr, nullptr,0,0,
       S1,0,512,64,  900,64,900, 1.f, 0, 8);
  gemm(S1,0,512,1,0,  mha_out_w,0,512,1,0,  mha_out_b, S0,512,0,
       S2,0,512,0,  900,512,512, 1.f, 1|4, 1);
  ln_k<<<900, 256, 0, stream>>>(S2, nullptr, nullptr, ln1_g, ln1_b, S1, nullptr, 0); // qn=S1

  gemm(S1,0,512,1,0, off_w1,0,512,1,0, off_b1, nullptr,0,0,
       S2,0,512,0, 900,512,512, 1.f, 1|2, 1);
  gemm(S2,0,512,1,0, off_w2,0,512,1,0, off_b2, nullptr,0,0,
       OFFB,0,8,0, 900,8,512, 1.f, 1, 1);
  gemm(S1,0,512,1,0, am_w1,0,512,1,0, am_b1, nullptr,0,0,
       S2,0,512,0, 900,512,512, 1.f, 1|2, 1);
  gemm(S2,0,512,1,0, am_w2,0,512,1,0, am_b2, nullptr,0,0,
       AMB,0,4,0, 900,4,512, 1.f, 1, 1);
  softmax4_k<<<4, 256, 0, stream>>>(AMB, 900);

  sample_prep_k<<<15, 256, 0, stream>>>(ref, OFFB, proj, CXY, VAL);
  grid_sample2_k<<<25200, 128, 0, stream>>>(imgT, CXY, X);   // overwrites SC (dead)

  // ---------------- transformer, depth 4 (bf16 MFMA) ----------------
  for (int L = 0; L < 4; ++L) {
    const float* g1  = t_ln1_g + L*512;  const float* bb1 = t_ln1_b + L*512;
    const float* bq  = t_in_b + L*1536;
    const float* bo  = t_out_b + L*512;
    const float* g2  = t_ln2_g + L*512;  const float* bb2 = t_ln2_b + L*512;
    const float* f1  = t_ff_b1 + L*512;
    const float* f2  = t_ff_b2 + L*512;
    const ushort* wq = Wqkvh + (long long)L*1536*512;
    const ushort* wo = Wouth + (long long)L*512*512;
    const ushort* w1 = Wff1h + (long long)L*512*512;
    const ushort* w2 = Wff2h + (long long)L*512*512;

    ln_k<<<25200, 256, 0, stream>>>(X, nullptr, nullptr, g1, bb1, nullptr, XNh, 0);
    for (int ch = 0; ch < 6; ++ch) {
      mgemm(XNh + (long long)ch*4200*512, wq, bq, nullptr, QKV, nullptr,
            4200, 1536, 512, 1);
      tf_attn_k<<<600, 256, 0, stream>>>(QKV, VAL, XNh, ch*600);  // in-place rows
    }
    mgemm(XNh, wo, bo, X, X, nullptr, 25200, 512, 512, 1|4);       // attn-proj + res
    ln_k<<<25200, 256, 0, stream>>>(X, nullptr, nullptr, g2, bb2, nullptr, XNh, 0);
    mgemm(XNh, w1, f1, nullptr, nullptr, Hh, 25200, 512, 512, 1|2|8); // ff1 -> bf16
    mgemm(Hh, w2, f2, X, X, nullptr, 25200, 512, 512, 1|4);        // ff2 + res
  }

  // ---------------- tail (fp32) ----------------
  pool_k<<<900, 256, 0, stream>>>(X, AMB, S3);
  gemm(S3,0,512,1,0, op_w,0,512,1,0, op_b, nullptr,0,0,
       S4,0,512,0, 900,512,512, 1.f, 1, 1);
  pe1_k<<<1800, 256, 0, stream>>>(ref, pe_w1, pe_bias1, S2);
  ln_k<<<900, 256, 0, stream>>>(S2, nullptr, nullptr, pe_ln1_g, pe_ln1_b, S5, nullptr, 1);
  gemm(S5,0,512,1,0, pe_w2,0,512,1,0, pe_bias2, nullptr,0,0,
       S2,0,512,0, 900,512,512, 1.f, 1, 1);
  ln_k<<<900, 256, 0, stream>>>(S2, nullptr, nullptr, pe_ln2_g, pe_ln2_b, S5, nullptr, 1);
  ln_k<<<900, 256, 0, stream>>>(S4, S1, S5, ln2_g, ln2_b, S3, nullptr, 0);   // qf=S3
  gemm(S3,0,512,1,0, ffn_w1,0,512,1,0, ffn_b1, nullptr,0,0,
       S2,0,512,0, 900,512,512, 1.f, 1|2, 1);
  gemm(S2,0,512,1,0, ffn_w2,0,512,1,0, ffn_b2, S3,512,0,
       S4,0,512,0, 900,512,512, 1.f, 1|4, 1);
  ln_k<<<900, 256, 0, stream>>>(S4, nullptr, nullptr, ln3_g, ln3_b, (float*)d_out, nullptr, 0);
}

// Round 4
// 2894.208 us; speedup vs baseline: 3.0013x; 1.3546x over previous
//
#include <hip/hip_runtime.h>
#include <hip/hip_bf16.h>

#define DEVI __device__ __forceinline__

typedef __bf16 bf16x8 __attribute__((ext_vector_type(8)));
typedef float f32x4 __attribute__((ext_vector_type(4)));

#define GLDS(gp, lp) __builtin_amdgcn_global_load_lds( \
    (const __attribute__((address_space(1))) void*)(gp), \
    (__attribute__((address_space(3))) void*)(lp), 16, 0, 0)

DEVI float b2f(ushort u) { unsigned v = ((unsigned)u) << 16; return __builtin_bit_cast(float, v); }
DEVI ushort f2bu(float x) { __hip_bfloat16 h = __float2bfloat16(x); return __builtin_bit_cast(ushort, h); }

// ============================================================================
// bf16 MFMA GEMM: C[m,n] = sum_k A[m,k]*W[n,k]  (+bias)(relu)(+R), K mult of 32,
// N mult of 128, A buffer padded to ceil(M/128)*128 rows.
// flags: 1=bias, 2=relu, 4=residual(fp32 R, ld=N), 8=write bf16 Cb instead of Cf
// ============================================================================
__global__ __launch_bounds__(256) void gemm_mfma_k(
    const ushort* __restrict__ Ah, const ushort* __restrict__ Wh,
    const float* __restrict__ bias, const float* Rp,
    float* Cf, ushort* Cb,
    int M, int N, int K, int flags)
{
  __shared__ ushort As[128 * 32];
  __shared__ ushort Bs[128 * 32];
  const int tid = threadIdx.x;
  const int lane = tid & 63;
  const int wid = tid >> 6;
  const int bn = blockIdx.x * 128;
  const int bm = blockIdx.y * 128;
  const int wr = wid >> 1, wc = wid & 1;
  const int col = lane & 15;
  const int ksl = lane >> 4;
  const int sr = lane >> 2;
  const int sd = lane & 3;

  f32x4 acc[4][4];
#pragma unroll
  for (int m = 0; m < 4; ++m)
#pragma unroll
    for (int n = 0; n < 4; ++n) acc[m][n] = (f32x4){0.f, 0.f, 0.f, 0.f};

  for (int k0 = 0; k0 < K; k0 += 32) {
#pragma unroll
    for (int j = 0; j < 2; ++j) {
      const int r = wid * 32 + j * 16 + sr;
      const int ss = sd ^ (r & 3);
      GLDS(Ah + (long long)(bm + r) * K + k0 + ss * 8, &As[(wid * 32 + j * 16) * 32]);
      GLDS(Wh + (long long)(bn + r) * K + k0 + ss * 8, &Bs[(wid * 32 + j * 16) * 32]);
    }
    __syncthreads();
    bf16x8 af[4], bf[4];
#pragma unroll
    for (int m = 0; m < 4; ++m) {
      const int r = wr * 64 + m * 16 + col;
      af[m] = *(const bf16x8*)&As[r * 32 + ((ksl ^ (r & 3)) << 3)];
    }
#pragma unroll
    for (int n = 0; n < 4; ++n) {
      const int r = wc * 64 + n * 16 + col;
      bf[n] = *(const bf16x8*)&Bs[r * 32 + ((ksl ^ (r & 3)) << 3)];
    }
#pragma unroll
    for (int m = 0; m < 4; ++m)
#pragma unroll
      for (int n = 0; n < 4; ++n)
        acc[m][n] = __builtin_amdgcn_mfma_f32_16x16x32_bf16(af[m], bf[n], acc[m][n], 0, 0, 0);
    __syncthreads();
  }

  const int r4 = (lane >> 4) * 4;
#pragma unroll
  for (int m = 0; m < 4; ++m) {
#pragma unroll
    for (int j = 0; j < 4; ++j) {
      const int row = bm + wr * 64 + m * 16 + r4 + j;
      if (row >= M) continue;
#pragma unroll
      for (int n = 0; n < 4; ++n) {
        const int cn = bn + wc * 64 + n * 16 + col;
        float v = acc[m][n][j];
        if (flags & 1) v += bias[cn];
        if (flags & 2) v = fmaxf(v, 0.f);
        if (flags & 4) v += Rp[(long long)row * N + cn];
        if (flags & 8) Cb[(long long)row * N + cn] = f2bu(v);
        else           Cf[(long long)row * N + cn] = v;
      }
    }
  }
}

// ============================================================================
// fp32 SGEMM (non-split; used for stage-1 scores only now)
// ============================================================================
__global__ __launch_bounds__(256) void gemm_k(
    const float* __restrict__ Ap, long long a_base, int a_rs, int a_cs, long long a_zs,
    const float* __restrict__ Wp, long long w_base, int w_rs, int w_cs, long long w_zs,
    const float* __restrict__ bias,
    const float* Rp, int r_rs, long long r_zs,
    float* Cp, long long c_base, int c_rs, long long c_zs,
    int M, int N, int K, float alpha, int flags)
{
  __shared__ float As[8][132];
  __shared__ float Bs[8][132];
  const int z = blockIdx.z;
  const float* A = Ap + a_base + (long long)z * a_zs;
  const float* W = Wp + w_base + (long long)z * w_zs;
  float* C = Cp + c_base + (long long)z * c_zs;
  const float* R = (flags & 4) ? (Rp + (long long)z * r_zs) : nullptr;

  const int bm = blockIdx.y * 128;
  const int bn = blockIdx.x * 128;
  const int tid = threadIdx.x;
  const int tx = tid & 15;
  const int ty = tid >> 4;
  const int srow = tid >> 1;
  const int k4 = (tid & 1) * 4;

  float acc[8][8];
#pragma unroll
  for (int i = 0; i < 8; ++i)
#pragma unroll
    for (int j = 0; j < 8; ++j) acc[i][j] = 0.f;

  const int am = bm + srow;
  const int wn = bn + srow;
  const bool am_ok = am < M;
  const bool wn_ok = wn < N;
  const long long aoff = (long long)(am_ok ? am : 0) * a_rs;
  const long long woff = (long long)(wn_ok ? wn : 0) * w_rs;

  for (int k0 = 0; k0 < K; k0 += 8) {
    if (a_cs == 1 && am_ok && (k0 + 8 <= K)) {
      float4 v = *(const float4*)(A + aoff + k0 + k4);
      As[k4+0][srow] = v.x; As[k4+1][srow] = v.y;
      As[k4+2][srow] = v.z; As[k4+3][srow] = v.w;
    } else {
#pragma unroll
      for (int j = 0; j < 4; ++j) {
        int kk = k0 + k4 + j;
        float va = 0.f;
        if (am_ok && kk < K) va = A[aoff + (long long)kk * a_cs];
        As[k4+j][srow] = va;
      }
    }
    if (w_cs == 1 && wn_ok && (k0 + 8 <= K)) {
      float4 v = *(const float4*)(W + woff + k0 + k4);
      Bs[k4+0][srow] = v.x; Bs[k4+1][srow] = v.y;
      Bs[k4+2][srow] = v.z; Bs[k4+3][srow] = v.w;
    } else {
#pragma unroll
      for (int j = 0; j < 4; ++j) {
        int kk = k0 + k4 + j;
        float vb = 0.f;
        if (wn_ok && kk < K) vb = W[woff + (long long)kk * w_cs];
        Bs[k4+j][srow] = vb;
      }
    }
    __syncthreads();
#pragma unroll
    for (int kk = 0; kk < 8; ++kk) {
      float af[8], bf[8];
      *(float4*)&af[0] = *(const float4*)&As[kk][ty*8];
      *(float4*)&af[4] = *(const float4*)&As[kk][ty*8+4];
      *(float4*)&bf[0] = *(const float4*)&Bs[kk][tx*4];
      *(float4*)&bf[4] = *(const float4*)&Bs[kk][64+tx*4];
#pragma unroll
      for (int i = 0; i < 8; ++i)
#pragma unroll
        for (int j = 0; j < 8; ++j)
          acc[i][j] = fmaf(af[i], bf[j], acc[i][j]);
    }
    __syncthreads();
  }

#pragma unroll
  for (int i = 0; i < 8; ++i) {
    int m = bm + ty*8 + i;
    if (m >= M) continue;
#pragma unroll
    for (int jg = 0; jg < 2; ++jg) {
#pragma unroll
      for (int j = 0; j < 4; ++j) {
        int n = bn + jg*64 + tx*4 + j;
        if (n >= N) continue;
        float v = acc[i][jg*4+j] * alpha;
        if (flags & 1) v += bias[n];
        if (flags & 2) v = fmaxf(v, 0.f);
        if (flags & 4) v += R[(long long)m * r_rs + n];
        C[(long long)m * c_rs + n] = v;
      }
    }
  }
}

// ============================================================================
// Split-K fp32 GEMM partial: P[(z*KS+ks)][M][N] = sum_{k in slice} A.W
// grid.z = Z*KS. No epilogue (done in sk_reduce_k).
// ============================================================================
__global__ __launch_bounds__(256) void gemm_sk_k(
    const float* __restrict__ Ap, long long a_base, int a_rs, int a_cs, long long a_zs,
    const float* __restrict__ Wp, long long w_base, int w_rs, int w_cs, long long w_zs,
    float* __restrict__ P,
    int M, int N, int K, int KS)
{
  __shared__ float As[8][132];
  __shared__ float Bs[8][132];
  const int zks = blockIdx.z;
  const int z = zks / KS, ks = zks % KS;
  const int klen = (K + KS - 1) / KS;
  const int kbeg = ks * klen;
  const int kend = min(K, kbeg + klen);
  const float* A = Ap + a_base + (long long)z * a_zs;
  const float* W = Wp + w_base + (long long)z * w_zs;

  const int bm = blockIdx.y * 128;
  const int bn = blockIdx.x * 128;
  const int tid = threadIdx.x;
  const int tx = tid & 15;
  const int ty = tid >> 4;
  const int srow = tid >> 1;
  const int k4 = (tid & 1) * 4;

  float acc[8][8];
#pragma unroll
  for (int i = 0; i < 8; ++i)
#pragma unroll
    for (int j = 0; j < 8; ++j) acc[i][j] = 0.f;

  const int am = bm + srow;
  const int wn = bn + srow;
  const bool am_ok = am < M;
  const bool wn_ok = wn < N;
  const long long aoff = (long long)(am_ok ? am : 0) * a_rs;
  const long long woff = (long long)(wn_ok ? wn : 0) * w_rs;

  for (int k0 = kbeg; k0 < kend; k0 += 8) {
    if (a_cs == 1 && am_ok && (k0 + 8 <= kend)) {
      float4 v = *(const float4*)(A + aoff + k0 + k4);
      As[k4+0][srow] = v.x; As[k4+1][srow] = v.y;
      As[k4+2][srow] = v.z; As[k4+3][srow] = v.w;
    } else {
#pragma unroll
      for (int j = 0; j < 4; ++j) {
        int kk = k0 + k4 + j;
        float va = 0.f;
        if (am_ok && kk < kend) va = A[aoff + (long long)kk * a_cs];
        As[k4+j][srow] = va;
      }
    }
    if (w_cs == 1 && wn_ok && (k0 + 8 <= kend)) {
      float4 v = *(const float4*)(W + woff + k0 + k4);
      Bs[k4+0][srow] = v.x; Bs[k4+1][srow] = v.y;
      Bs[k4+2][srow] = v.z; Bs[k4+3][srow] = v.w;
    } else {
#pragma unroll
      for (int j = 0; j < 4; ++j) {
        int kk = k0 + k4 + j;
        float vb = 0.f;
        if (wn_ok && kk < kend) vb = W[woff + (long long)kk * w_cs];
        Bs[k4+j][srow] = vb;
      }
    }
    __syncthreads();
#pragma unroll
    for (int kk = 0; kk < 8; ++kk) {
      float af[8], bf[8];
      *(float4*)&af[0] = *(const float4*)&As[kk][ty*8];
      *(float4*)&af[4] = *(const float4*)&As[kk][ty*8+4];
      *(float4*)&bf[0] = *(const float4*)&Bs[kk][tx*4];
      *(float4*)&bf[4] = *(const float4*)&Bs[kk][64+tx*4];
#pragma unroll
      for (int i = 0; i < 8; ++i)
#pragma unroll
        for (int j = 0; j < 8; ++j)
          acc[i][j] = fmaf(af[i], bf[j], acc[i][j]);
    }
    __syncthreads();
  }

  float* Pz = P + ((long long)zks * M) * N;
#pragma unroll
  for (int i = 0; i < 8; ++i) {
    int m = bm + ty*8 + i;
    if (m >= M) continue;
#pragma unroll
    for (int jg = 0; jg < 2; ++jg) {
#pragma unroll
      for (int j = 0; j < 4; ++j) {
        int n = bn + jg*64 + tx*4 + j;
        if (n >= N) continue;
        Pz[(long long)m * N + n] = acc[i][jg*4+j];
      }
    }
  }
}

// reduce KS partials + epilogue. grid: (ceil(M*N/256), Z)
__global__ __launch_bounds__(256) void sk_reduce_k(
    const float* __restrict__ P, int M, int N, int KS, float alpha,
    const float* __restrict__ bias, const float* Rp, int r_rs, long long r_zs,
    float* Cp, long long c_base, int c_rs, long long c_zs, int flags)
{
  long long idx = (long long)blockIdx.x * 256 + threadIdx.x;
  if (idx >= (long long)M * N) return;
  const int z = blockIdx.y;
  const int m = (int)(idx / N), n = (int)(idx % N);
  const long long mn = (long long)M * N;
  const float* p = P + (long long)z * KS * mn + idx;
  float s = 0.f;
  for (int ks = 0; ks < KS; ++ks) s += p[(long long)ks * mn];
  s *= alpha;
  if (flags & 1) s += bias[n];
  if (flags & 2) s = fmaxf(s, 0.f);
  if (flags & 4) s += Rp[(long long)z * r_zs + (long long)m * r_rs + n];
  Cp[c_base + (long long)z * c_zs + (long long)m * c_rs + n] = s;
}

// tall-skinny head: out[m, 0..N) = A[m,:512] . W[n,:512] + bias, N <= 8
__global__ __launch_bounds__(256) void head_k(
    const float* __restrict__ A, const float* __restrict__ W,
    const float* __restrict__ bias, float* __restrict__ out, int N)
{
  __shared__ float red[4][8];
  const int m = blockIdx.x;
  const int tid = threadIdx.x, lane = tid & 63, w = tid >> 6;
  const float a0 = A[(long long)m * 512 + tid];
  const float a1 = A[(long long)m * 512 + tid + 256];
  for (int n = 0; n < N; ++n) {
    float p = a0 * W[n*512 + tid] + a1 * W[n*512 + tid + 256];
#pragma unroll
    for (int off = 32; off > 0; off >>= 1) p += __shfl_down(p, off, 64);
    if (lane == 0) red[w][n] = p;
  }
  __syncthreads();
  if (tid < N) out[(long long)m * N + tid] = red[0][tid]+red[1][tid]+red[2][tid]+red[3][tid] + bias[tid];
}

// ============================================================================
// LayerNorm over E=512; fused add of up to 2 extras; optional relu;
// writes fp32 to outp (if non-null) and/or bf16 to outb (if non-null).
// ============================================================================
__global__ __launch_bounds__(256) void ln_k(
    const float* __restrict__ in0, const float* __restrict__ in1, const float* __restrict__ in2,
    const float* __restrict__ g, const float* __restrict__ b,
    float* __restrict__ outp, ushort* __restrict__ outb, int relu)
{
  __shared__ float red[8];
  const long long base = (long long)blockIdx.x * 512;
  const int tid = threadIdx.x;
  float x0 = in0[base + tid];
  float x1 = in0[base + tid + 256];
  if (in1) { x0 += in1[base + tid]; x1 += in1[base + tid + 256]; }
  if (in2) { x0 += in2[base + tid]; x1 += in2[base + tid + 256]; }
  float s = x0 + x1, q = x0*x0 + x1*x1;
#pragma unroll
  for (int off = 32; off > 0; off >>= 1) {
    s += __shfl_down(s, off, 64);
    q += __shfl_down(q, off, 64);
  }
  if ((tid & 63) == 0) { red[tid >> 6] = s; red[4 + (tid >> 6)] = q; }
  __syncthreads();
  if (tid == 0) {
    float S = red[0]+red[1]+red[2]+red[3];
    float Q = red[4]+red[5]+red[6]+red[7];
    float m = S * (1.f/512.f);
    float v = Q * (1.f/512.f) - m*m;
    red[0] = m; red[1] = rsqrtf(v + 1e-5f);
  }
  __syncthreads();
  float m = red[0], inv = red[1];
  float y0 = (x0 - m) * inv * g[tid]     + b[tid];
  float y1 = (x1 - m) * inv * g[tid+256] + b[tid+256];
  if (relu) { y0 = fmaxf(y0, 0.f); y1 = fmaxf(y1, 0.f); }
  if (outp) {
    outp[base + tid]       = y0;
    outp[base + tid + 256] = y1;
  }
  if (outb) {
    outb[base + tid]       = f2bu(y0);
    outb[base + tid + 256] = f2bu(y1);
  }
}

__global__ __launch_bounds__(256) void softmax_k(float* __restrict__ p, int S)
{
  __shared__ float red[8];
  float* r = p + (long long)blockIdx.x * S;
  const int tid = threadIdx.x;
  float vals[4];
  int cnt = 0;
  float mx = -3.0e38f;
  for (int e = tid; e < S; e += 256) { float v = r[e]; vals[cnt++] = v; mx = fmaxf(mx, v); }
#pragma unroll
  for (int off = 32; off > 0; off >>= 1) mx = fmaxf(mx, __shfl_down(mx, off, 64));
  if ((tid & 63) == 0) red[tid >> 6] = mx;
  __syncthreads();
  if (tid == 0) red[0] = fmaxf(fmaxf(red[0], red[1]), fmaxf(red[2], red[3]));
  __syncthreads();
  mx = red[0];
  float sum = 0.f;
  for (int i = 0; i < cnt; ++i) { vals[i] = expf(vals[i] - mx); sum += vals[i]; }
#pragma unroll
  for (int off = 32; off > 0; off >>= 1) sum += __shfl_down(sum, off, 64);
  if ((tid & 63) == 0) red[4 + (tid >> 6)] = sum;
  __syncthreads();
  if (tid == 0) red[4] = red[4]+red[5]+red[6]+red[7];
  __syncthreads();
  float inv = 1.f / red[4];
  cnt = 0;
  for (int e = tid; e < S; e += 256) r[e] = vals[cnt++] * inv;
}

__global__ __launch_bounds__(256) void softmax4_k(float* __restrict__ p, int rows)
{
  int i = blockIdx.x * 256 + threadIdx.x;
  if (i >= rows) return;
  float* r = p + (long long)i * 4;
  float m = fmaxf(fmaxf(r[0], r[1]), fmaxf(r[2], r[3]));
  float e0 = expf(r[0]-m), e1 = expf(r[1]-m), e2 = expf(r[2]-m), e3 = expf(r[3]-m);
  float inv = 1.f / (e0+e1+e2+e3);
  r[0] = e0*inv; r[1] = e1*inv; r[2] = e2*inv; r[3] = e3*inv;
}

__global__ __launch_bounds__(256) void add2_k(
    const float* __restrict__ a, const float* __restrict__ b, float* __restrict__ o, int n)
{
  int i = blockIdx.x * 256 + threadIdx.x;
  if (i < n) o[i] = a[i] + b[i];
}

__global__ __launch_bounds__(256) void f2b_k(
    const float* __restrict__ in, ushort* __restrict__ out, int n)
{
  int i = blockIdx.x * 256 + threadIdx.x;
  if (i < n) out[i] = f2bu(in[i]);
}

DEVI float inv_sig(float x)
{
  x = fminf(fmaxf(x, 0.f), 1.f);
  float a = fmaxf(x, 1e-5f);
  float c = fmaxf(1.f - x, 1e-5f);
  return logf(a / c);
}

__global__ __launch_bounds__(256) void sample_prep_k(
    const float* __restrict__ ref, const float* __restrict__ offs,
    const float* __restrict__ proj, float* __restrict__ camxy, float* __restrict__ valid)
{
  int n = blockIdx.x * 256 + threadIdx.x;
  if (n >= 3600) return;
  int qq = n >> 2, pp = n & 3;
  int rrow = n % 900;
  float tx = inv_sig(ref[rrow*2+0]) + offs[qq*8 + pp*2 + 0];
  float ty = inv_sig(ref[rrow*2+1]) + offs[qq*8 + pp*2 + 1];
  float sx = 1.f / (1.f + expf(-tx));
  float sy = 1.f / (1.f + expf(-ty));
  float px = sx * 480.f, py = sy * 1440.f;
#pragma unroll
  for (int c = 0; c < 7; ++c) {
    const float* M = proj + c*9;
    float icx = M[0]*px + M[1]*py + M[2];
    float icy = M[3]*px + M[4]*py + M[5];
    float icz = M[6]*px + M[7]*py + M[8];
    float zc = fmaxf(icz, 1e-5f);
    float cx = (icx/zc/1920.f - 0.5f) * 2.f;
    float cy = (icy/zc/1080.f - 0.5f) * 2.f;
    int ok = (icz > 1e-5f) && (cx > -1.f) && (cx < 1.f) && (cy > -1.f) && (cy < 1.f);
    camxy[((long long)c*3600+n)*2+0] = cx;
    camxy[((long long)c*3600+n)*2+1] = cy;
    valid[(long long)c*3600+n] = ok ? 1.f : 0.f;
  }
}

// img [7][512][8160] fp32 -> imgT [7][8160][512] bf16
__global__ __launch_bounds__(256) void timg_k(
    const float* __restrict__ img, ushort* __restrict__ out)
{
  __shared__ float t[32][33];
  const int cam = blockIdx.z;
  const int hw0 = blockIdx.x * 32;
  const int c0  = blockIdx.y * 32;
  const int tx = threadIdx.x & 31, ty = threadIdx.x >> 5;
  const float* src = img + ((long long)cam * 512 + c0) * 8160 + hw0;
#pragma unroll
  for (int i = 0; i < 4; ++i)
    t[ty + i*8][tx] = src[(long long)(ty + i*8) * 8160 + tx];
  __syncthreads();
  ushort* dst = out + ((long long)cam * 8160 + hw0) * 512 + c0;
#pragma unroll
  for (int i = 0; i < 4; ++i)
    dst[(long long)(ty + i*8) * 512 + tx] = f2bu(t[tx][ty + i*8]);
}

__global__ __launch_bounds__(128) void grid_sample2_k(
    const ushort* __restrict__ imgT, const float* __restrict__ camxy,
    float* __restrict__ xout)
{
  const int blk = blockIdx.x;
  const int pt = blk / 7, cam = blk % 7;
  float gx = camxy[((long long)cam*3600+pt)*2+0];
  float gy = camxy[((long long)cam*3600+pt)*2+1];
  float fx = (gx + 1.f) * 60.f - 0.5f;
  float fy = (gy + 1.f) * 34.f - 0.5f;
  float x0f = floorf(fx), y0f = floorf(fy);
  float wx1 = fx - x0f, wy1 = fy - y0f;
  float wx0 = 1.f - wx1, wy0 = 1.f - wy1;
  x0f = fminf(fmaxf(x0f, -2.e9f), 2.e9f);
  y0f = fminf(fmaxf(y0f, -2.e9f), 2.e9f);
  int x0 = (int)x0f, y0 = (int)y0f;
  int x1 = x0 + 1, y1 = y0 + 1;
  bool okx0 = (x0 >= 0) && (x0 < 120);
  bool okx1 = (x1 >= 0) && (x1 < 120);
  bool oky0 = (y0 >= 0) && (y0 < 68);
  bool oky1 = (y1 >= 0) && (y1 < 68);
  int cx0 = min(max(x0,0),119), cx1 = min(max(x1,0),119);
  int cy0 = min(max(y0,0),67),  cy1 = min(max(y1,0),67);
  float w00 = (okx0 && oky0) ? wy0*wx0 : 0.f;
  float w01 = (okx1 && oky0) ? wy0*wx1 : 0.f;
  float w10 = (okx0 && oky1) ? wy1*wx0 : 0.f;
  float w11 = (okx1 && oky1) ? wy1*wx1 : 0.f;
  const long long i00 = (long long)(cy0*120+cx0) * 512;
  const long long i01 = (long long)(cy0*120+cx1) * 512;
  const long long i10 = (long long)(cy1*120+cx0) * 512;
  const long long i11 = (long long)(cy1*120+cx1) * 512;
  const ushort* f = imgT + (long long)cam * 8160 * 512;
  float* o = xout + (long long)blk * 512;
  const int c = threadIdx.x * 4;
  ushort4 u00 = *(const ushort4*)(f + i00 + c);
  ushort4 u01 = *(const ushort4*)(f + i01 + c);
  ushort4 u10 = *(const ushort4*)(f + i10 + c);
  ushort4 u11 = *(const ushort4*)(f + i11 + c);
  float4 r;
  r.x = b2f(u00.x)*w00 + b2f(u01.x)*w01 + b2f(u10.x)*w10 + b2f(u11.x)*w11;
  r.y = b2f(u00.y)*w00 + b2f(u01.y)*w01 + b2f(u10.y)*w10 + b2f(u11.y)*w11;
  r.z = b2f(u00.z)*w00 + b2f(u01.z)*w01 + b2f(u10.z)*w10 + b2f(u11.z)*w11;
  r.w = b2f(u00.w)*w00 + b2f(u01.w)*w01 + b2f(u10.w)*w10 + b2f(u11.w)*w11;
  *(float4*)(o + c) = r;
}

// Per-batch 7-token MHA; qkv = this chunk's rows fp32; out bf16 at GLOBAL rows.
__global__ __launch_bounds__(256) void tf_attn_k(
    const float* __restrict__ qkv, const float* __restrict__ valid,
    ushort* __restrict__ outp, int batch0)
{
  __shared__ float sv[7*1536];
  const int lb = blockIdx.x;
  const int ib = batch0 + lb;
  const float4* src = (const float4*)(qkv + (long long)lb * (7*1536));
  float4* dst4 = (float4*)sv;
  for (int idx = threadIdx.x; idx < 7*1536/4; idx += 256) dst4[idx] = src[idx];
  __syncthreads();
  const int tid = threadIdx.x;
  if (tid < 56) {
    const int h = tid / 7, sq = tid % 7;
    const int bb = ib*8 + h;
    const int pp = bb / 7200;
    const int rr = (bb - pp*7200) % 900;
    const float* qrow = sv + sq*1536 + h*64;
    float sc[7];
    float mx = -3.0e38f;
#pragma unroll
    for (int t = 0; t < 7; ++t) {
      const float* krow = sv + t*1536 + 512 + h*64;
      float d = 0.f;
      for (int e = 0; e < 64; ++e) d = fmaf(qrow[e], krow[e], d);
      d *= 0.125f;
      if (valid[(long long)t*3600 + rr*4 + pp] == 0.f) d = -1e9f;
      sc[t] = d;
      mx = fmaxf(mx, d);
    }
    float sum = 0.f;
#pragma unroll
    for (int t = 0; t < 7; ++t) { sc[t] = expf(sc[t] - mx); sum += sc[t]; }
    float inv = 1.f / sum;
#pragma unroll
    for (int t = 0; t < 7; ++t) sc[t] *= inv;
    ushort* orow = outp + ((long long)ib*7 + sq)*512 + h*64;
    for (int e = 0; e < 64; e += 4) {
      float a0=0.f, a1=0.f, a2=0.f, a3=0.f;
#pragma unroll
      for (int t = 0; t < 7; ++t) {
        const float* vr = sv + t*1536 + 1024 + h*64 + e;
        float w = sc[t];
        a0 = fmaf(w, vr[0], a0); a1 = fmaf(w, vr[1], a1);
        a2 = fmaf(w, vr[2], a2); a3 = fmaf(w, vr[3], a3);
      }
      ushort4 st;
      st.x = f2bu(a0); st.y = f2bu(a1); st.z = f2bu(a2); st.w = f2bu(a3);
      *(ushort4*)orow = st;
      orow += 4;
    }
  }
}

// pooled (bf16 out for MFMA consumption)
__global__ __launch_bounds__(256) void pool_k(
    const float* __restrict__ x, const float* __restrict__ aw, ushort* __restrict__ o)
{
  int qq = blockIdx.x;
  for (int c = threadIdx.x; c < 512; c += 256) {
    float acc = 0.f;
#pragma unroll
    for (int p = 0; p < 4; ++p) {
      const float* xr = x + ((long long)(qq*4+p)*7)*512 + c;
      float s = 0.f;
#pragma unroll
      for (int cam = 0; cam < 7; ++cam) s += xr[cam*512];
      acc = fmaf(s, aw[qq*4+p], acc);
    }
    o[(long long)qq*512 + c] = f2bu(acc * (1.f/28.f));
  }
}

__global__ __launch_bounds__(256) void pe1_k(
    const float* __restrict__ ref, const float* __restrict__ w1, const float* __restrict__ b1,
    float* __restrict__ o)
{
  int idx = blockIdx.x * 256 + threadIdx.x;
  if (idx >= 900*512) return;
  int qq = idx >> 9, c = idx & 511;
  float i0 = inv_sig(ref[qq*2+0]);
  float i1 = inv_sig(ref[qq*2+1]);
  o[idx] = i0*w1[c*2+0] + i1*w1[c*2+1] + b1[c];
}

// ============================================================================
extern "C" void kernel_launch(void* const* d_in, const int* in_sizes, int n_in,
                              void* d_out, int out_size, void* d_ws, size_t ws_size,
                              hipStream_t stream)
{
  (void)in_sizes; (void)n_in; (void)out_size;
  const float* img      = (const float*)d_in[0];
  const float* proj     = (const float*)d_in[1];
  const float* query    = (const float*)d_in[2];
  const float* qpos     = (const float*)d_in[3];
  const float* ref      = (const float*)d_in[4];
  const float* mha_in_w = (const float*)d_in[5];
  const float* mha_in_b = (const float*)d_in[6];
  const float* mha_out_w= (const float*)d_in[7];
  const float* mha_out_b= (const float*)d_in[8];
  const float* off_w1   = (const float*)d_in[9];
  const float* off_b1   = (const float*)d_in[10];
  const float* off_w2   = (const float*)d_in[11];
  const float* off_b2   = (const float*)d_in[12];
  const float* am_w1    = (const float*)d_in[13];
  const float* am_b1    = (const float*)d_in[14];
  const float* am_w2    = (const float*)d_in[15];
  const float* am_b2    = (const float*)d_in[16];
  const float* t_ln1_g  = (const float*)d_in[17];
  const float* t_ln1_b  = (const float*)d_in[18];
  const float* t_in_w   = (const float*)d_in[19];
  const float* t_in_b   = (const float*)d_in[20];
  const float* t_out_w  = (const float*)d_in[21];
  const float* t_out_b  = (const float*)d_in[22];
  const float* t_ln2_g  = (const float*)d_in[23];
  const float* t_ln2_b  = (const float*)d_in[24];
  const float* t_ff_w1  = (const float*)d_in[25];
  const float* t_ff_b1  = (const float*)d_in[26];
  const float* t_ff_w2  = (const float*)d_in[27];
  const float* t_ff_b2  = (const float*)d_in[28];
  const float* ffn_w1   = (const float*)d_in[29];
  const float* ffn_b1   = (const float*)d_in[30];
  const float* ffn_w2   = (const float*)d_in[31];
  const float* ffn_b2   = (const float*)d_in[32];
  const float* op_w     = (const float*)d_in[33];
  const float* op_b     = (const float*)d_in[34];
  const float* pe_w1    = (const float*)d_in[35];
  const float* pe_bias1 = (const float*)d_in[36];
  const float* pe_ln1_g = (const float*)d_in[37];
  const float* pe_ln1_b = (const float*)d_in[38];
  const float* pe_w2    = (const float*)d_in[39];
  const float* pe_bias2 = (const float*)d_in[40];
  const float* pe_ln2_g = (const float*)d_in[41];
  const float* pe_ln2_b = (const float*)d_in[42];
  const float* ln1_g    = (const float*)d_in[43];
  const float* ln1_b    = (const float*)d_in[44];
  const float* ln2_g    = (const float*)d_in[45];
  const float* ln2_b    = (const float*)d_in[46];
  const float* ln3_g    = (const float*)d_in[47];
  const float* ln3_b    = (const float*)d_in[48];

  char* wsb = (char*)d_ws;
  size_t off = 0;
  auto alloc = [&](long long bytes) -> char* {
    char* p = wsb + off;
    off += (size_t)((bytes + 255) / 256 * 256);
    return p;
  };
  float* X    = (float*)alloc(25200ll * 512 * 4);      // tokens; SC + split-K partials overlay pre-sample
  float* QKV  = (float*)alloc(4200ll * 1536 * 4);
  char*  R1   = alloc(7ll * 8160 * 512 * 2);
  ushort* imgT = (ushort*)R1;
  ushort* XNh  = (ushort*)R1;                          // [25344][512]
  ushort* Hh   = (ushort*)(R1 + 25344ll * 512 * 2);
  ushort* Wqkvh = (ushort*)alloc(4ll * 1536 * 512 * 2);
  ushort* Wouth = (ushort*)alloc(4ll * 512 * 512 * 2);
  ushort* Wff1h = (ushort*)alloc(4ll * 512 * 512 * 2);
  ushort* Wff2h = (ushort*)alloc(4ll * 512 * 512 * 2);
  ushort* Wtailh = (ushort*)alloc(4ll * 512 * 512 * 2); // op_w, pe_w2, ffn_w1, ffn_w2
  ushort* PoolH = (ushort*)alloc(1024ll * 512 * 2);
  ushort* PEh   = (ushort*)alloc(1024ll * 512 * 2);
  ushort* S3h   = (ushort*)alloc(1024ll * 512 * 2);
  ushort* Hh2   = (ushort*)alloc(1024ll * 512 * 2);
  float* S0   = (float*)alloc(900ll * 512 * 4);
  float* S1   = (float*)alloc(900ll * 512 * 4);
  float* S2   = (float*)alloc(900ll * 512 * 4);
  float* S3   = (float*)alloc(900ll * 512 * 4);
  float* S4   = (float*)alloc(900ll * 512 * 4);
  float* S5   = (float*)alloc(900ll * 512 * 4);
  float* OFFB = (float*)alloc(900ll * 8 * 4);
  float* AMB  = (float*)alloc(900ll * 4 * 4);
  float* CXY  = (float*)alloc(7ll * 3600 * 2 * 4);
  float* VAL  = (float*)alloc(7ll * 3600 * 4);
  if (off > ws_size) return;

  float* SC  = X;                 // [8][900][900] scores (dead before sampling)
  float* P1  = X;                 // qkv1 split-K partials (8*900*1536 floats, before SC)
  float* P2  = X + 6500000;       // split-K partials after SC live (PV/proj/mlp)
  float* QKV1 = QKV;

  auto gemm = [&](const float* A, long long ab, int ars, int acs, long long azs,
                  const float* W, long long wb, int wrs, int wcs, long long wzs,
                  const float* bias, const float* R, int rrs, long long rzs,
                  float* C, long long cb, int crs, long long czs,
                  int M, int N, int K, float alpha, int flags, int Z) {
    dim3 grd((unsigned)((N + 127) / 128), (unsigned)((M + 127) / 128), (unsigned)Z);
    gemm_k<<<grd, dim3(256), 0, stream>>>(A, ab, ars, acs, azs, W, wb, wrs, wcs, wzs,
                                          bias, R, rrs, rzs, C, cb, crs, czs,
                                          M, N, K, alpha, flags);
  };
  // split-K GEMM + reduce
  auto skgemm = [&](const float* A, long long ab, int ars, int acs, long long azs,
                    const float* W, long long wb, int wrs, int wcs, long long wzs,
                    float* P, const float* bias, const float* R, int rrs, long long rzs,
                    float* C, long long cb, int crs, long long czs,
                    int M, int N, int K, float alpha, int flags, int Z, int KS) {
    dim3 grd((unsigned)((N + 127) / 128), (unsigned)((M + 127) / 128), (unsigned)(Z * KS));
    gemm_sk_k<<<grd, dim3(256), 0, stream>>>(A, ab, ars, acs, azs, W, wb, wrs, wcs, wzs,
                                             P, M, N, K, KS);
    dim3 grd2((unsigned)(((long long)M * N + 255) / 256), (unsigned)Z);
    sk_reduce_k<<<grd2, dim3(256), 0, stream>>>(P, M, N, KS, alpha, bias, R, rrs, rzs,
                                                C, cb, crs, czs, flags);
  };
  auto mgemm = [&](const ushort* A, const ushort* W, const float* bias,
                   const float* R, float* Cf, ushort* Cb,
                   int M, int N, int K, int flags) {
    dim3 grd((unsigned)(N / 128), (unsigned)((M + 127) / 128), 1);
    gemm_mfma_k<<<grd, dim3(256), 0, stream>>>(A, W, bias, R, Cf, Cb, M, N, K, flags);
  };

  // weight conversion
  f2b_k<<<(4*1536*512+255)/256, 256, 0, stream>>>(t_in_w,  Wqkvh, 4*1536*512);
  f2b_k<<<(4*512*512+255)/256, 256, 0, stream>>>(t_out_w, Wouth, 4*512*512);
  f2b_k<<<(4*512*512+255)/256, 256, 0, stream>>>(t_ff_w1, Wff1h, 4*512*512);
  f2b_k<<<(4*512*512+255)/256, 256, 0, stream>>>(t_ff_w2, Wff2h, 4*512*512);
  f2b_k<<<(512*512+255)/256, 256, 0, stream>>>(op_w,   Wtailh + 0ll*512*512, 512*512);
  f2b_k<<<(512*512+255)/256, 256, 0, stream>>>(pe_w2,  Wtailh + 1ll*512*512, 512*512);
  f2b_k<<<(512*512+255)/256, 256, 0, stream>>>(ffn_w1, Wtailh + 2ll*512*512, 512*512);
  f2b_k<<<(512*512+255)/256, 256, 0, stream>>>(ffn_w2, Wtailh + 3ll*512*512, 512*512);
  timg_k<<<dim3(255, 16, 7), 256, 0, stream>>>(img, imgT);

  // ---------------- stage 1 (fp32, split-K) ----------------
  add2_k<<<1800, 256, 0, stream>>>(query, qpos, S0, 460800);
  skgemm(S0,0,512,1,0,  mha_in_w,0,512,1,0,  P1, mha_in_b, nullptr,0,0,
         QKV1,0,1536,0,  900,1536,512, 1.f, 1, 1, 8);
  gemm(QKV1,0,1536,1,64,  QKV1,512,1536,1,64,  nullptr, nullptr,0,0,
       SC,0,900,810000,  900,900,64, 0.125f, 0, 8);
  softmax_k<<<7200, 256, 0, stream>>>(SC, 900);
  skgemm(SC,0,900,1,810000,  QKV1,1024,1,1536,64,  P2, nullptr, nullptr,0,0,
         S1,0,512,64,  900,64,900, 1.f, 0, 8, 8);
  skgemm(S1,0,512,1,0,  mha_out_w,0,512,1,0,  P2, mha_out_b, S0,512,0,
         S2,0,512,0,  900,512,512, 1.f, 1|4, 1, 8);
  ln_k<<<900, 256, 0, stream>>>(S2, nullptr, nullptr, ln1_g, ln1_b, S1, nullptr, 0); // qn=S1

  skgemm(S1,0,512,1,0, off_w1,0,512,1,0, P2, off_b1, nullptr,0,0,
         S2,0,512,0, 900,512,512, 1.f, 1|2, 1, 8);
  head_k<<<900, 256, 0, stream>>>(S2, off_w2, off_b2, OFFB, 8);
  skgemm(S1,0,512,1,0, am_w1,0,512,1,0, P2, am_b1, nullptr,0,0,
         S2,0,512,0, 900,512,512, 1.f, 1|2, 1, 8);
  head_k<<<900, 256, 0, stream>>>(S2, am_w2, am_b2, AMB, 4);
  softmax4_k<<<4, 256, 0, stream>>>(AMB, 900);

  sample_prep_k<<<15, 256, 0, stream>>>(ref, OFFB, proj, CXY, VAL);
  grid_sample2_k<<<25200, 128, 0, stream>>>(imgT, CXY, X);

  // ---------------- transformer, depth 4 (bf16 MFMA) ----------------
  for (int L = 0; L < 4; ++L) {
    const float* g1  = t_ln1_g + L*512;  const float* bb1 = t_ln1_b + L*512;
    const float* bq  = t_in_b + L*1536;
    const float* bo  = t_out_b + L*512;
    const float* g2  = t_ln2_g + L*512;  const float* bb2 = t_ln2_b + L*512;
    const float* f1  = t_ff_b1 + L*512;
    const float* f2  = t_ff_b2 + L*512;
    const ushort* wq = Wqkvh + (long long)L*1536*512;
    const ushort* wo = Wouth + (long long)L*512*512;
    const ushort* w1 = Wff1h + (long long)L*512*512;
    const ushort* w2 = Wff2h + (long long)L*512*512;

    ln_k<<<25200, 256, 0, stream>>>(X, nullptr, nullptr, g1, bb1, nullptr, XNh, 0);
    for (int ch = 0; ch < 6; ++ch) {
      mgemm(XNh + (long long)ch*4200*512, wq, bq, nullptr, QKV, nullptr,
            4200, 1536, 512, 1);
      tf_attn_k<<<600, 256, 0, stream>>>(QKV, VAL, XNh, ch*600);
    }
    mgemm(XNh, wo, bo, X, X, nullptr, 25200, 512, 512, 1|4);
    ln_k<<<25200, 256, 0, stream>>>(X, nullptr, nullptr, g2, bb2, nullptr, XNh, 0);
    mgemm(XNh, w1, f1, nullptr, nullptr, Hh, 25200, 512, 512, 1|2|8);
    mgemm(Hh, w2, f2, X, X, nullptr, 25200, 512, 512, 1|4);
  }

  // ---------------- tail (bf16 MFMA) ----------------
  pool_k<<<900, 256, 0, stream>>>(X, AMB, PoolH);
  mgemm(PoolH, Wtailh + 0ll*512*512, op_b, nullptr, S4, nullptr, 900, 512, 512, 1);
  pe1_k<<<1800, 256, 0, stream>>>(ref, pe_w1, pe_bias1, S2);
  ln_k<<<900, 256, 0, stream>>>(S2, nullptr, nullptr, pe_ln1_g, pe_ln1_b, nullptr, PEh, 1);
  mgemm(PEh, Wtailh + 1ll*512*512, pe_bias2, nullptr, S2, nullptr, 900, 512, 512, 1);
  ln_k<<<900, 256, 0, stream>>>(S2, nullptr, nullptr, pe_ln2_g, pe_ln2_b, S5, nullptr, 1);
  ln_k<<<900, 256, 0, stream>>>(S4, S1, S5, ln2_g, ln2_b, S3, S3h, 0);       // qf
  mgemm(S3h, Wtailh + 2ll*512*512, ffn_b1, nullptr, nullptr, Hh2, 900, 512, 512, 1|2|8);
  mgemm(Hh2, Wtailh + 3ll*512*512, ffn_b2, S3, S4, nullptr, 900, 512, 512, 1|4);
  ln_k<<<900, 256, 0, stream>>>(S4, nullptr, nullptr, ln3_g, ln3_b, (float*)d_out, nullptr, 0);
}

// Round 5
// 2838.746 us; speedup vs baseline: 3.0600x; 1.0195x over previous
//
#include <hip/hip_runtime.h>
#include <hip/hip_bf16.h>

#define DEVI __device__ __forceinline__

typedef __bf16 bf16x8 __attribute__((ext_vector_type(8)));
typedef float f32x4 __attribute__((ext_vector_type(4)));

#define GLDS(gp, lp) __builtin_amdgcn_global_load_lds( \
    (const __attribute__((address_space(1))) void*)(gp), \
    (__attribute__((address_space(3))) void*)(lp), 16, 0, 0)

DEVI float b2f(ushort u) { unsigned v = ((unsigned)u) << 16; return __builtin_bit_cast(float, v); }
DEVI ushort f2bu(float x) { __hip_bfloat16 h = __float2bfloat16(x); return __builtin_bit_cast(ushort, h); }

// ============================================================================
// bf16 MFMA GEMM, double-buffered prefetch (T3 minimum 2-phase):
// C[m,n] = sum_k A[m,k]*W[n,k] (+bias)(relu)(+R). K mult of 32, N mult of 128,
// A/W buffers padded to ceil(M/128)*128 rows.
// flags: 1=bias, 2=relu, 4=residual(fp32 R, ld=N), 8=write bf16 Cb instead of Cf
// 128x128 tile, BK=32, 4 waves (2x2 of 64x64), 16x16x32 MFMA, slot-swizzled LDS.
// ============================================================================
__global__ __launch_bounds__(256) void gemm_mfma_k(
    const ushort* __restrict__ Ah, const ushort* __restrict__ Wh,
    const float* __restrict__ bias, const float* Rp,
    float* Cf, ushort* Cb,
    int M, int N, int K, int flags)
{
  __shared__ ushort As[2][128 * 32];
  __shared__ ushort Bs[2][128 * 32];
  const int tid = threadIdx.x;
  const int lane = tid & 63;
  const int wid = tid >> 6;
  const int bn = blockIdx.x * 128;
  const int bm = blockIdx.y * 128;
  const int wr = wid >> 1, wc = wid & 1;
  const int col = lane & 15;
  const int ksl = lane >> 4;

  f32x4 acc[4][4];
#pragma unroll
  for (int m = 0; m < 4; ++m)
#pragma unroll
    for (int n = 0; n < 4; ++n) acc[m][n] = (f32x4){0.f, 0.f, 0.f, 0.f};

  auto stage = [&](int buf, int t) {
#pragma unroll
    for (int j = 0; j < 2; ++j) {
      const int r = wid * 32 + j * 16 + (lane >> 2);
      const int ss = (lane & 3) ^ (r & 3);
      GLDS(Ah + (long long)(bm + r) * K + t * 32 + ss * 8, &As[buf][(wid * 32 + j * 16) * 32]);
      GLDS(Wh + (long long)(bn + r) * K + t * 32 + ss * 8, &Bs[buf][(wid * 32 + j * 16) * 32]);
    }
  };
  auto compute = [&](int buf) {
    bf16x8 af[4], bf[4];
#pragma unroll
    for (int m = 0; m < 4; ++m) {
      const int r = wr * 64 + m * 16 + col;
      af[m] = *(const bf16x8*)&As[buf][r * 32 + ((ksl ^ (r & 3)) << 3)];
    }
#pragma unroll
    for (int n = 0; n < 4; ++n) {
      const int r = wc * 64 + n * 16 + col;
      bf[n] = *(const bf16x8*)&Bs[buf][r * 32 + ((ksl ^ (r & 3)) << 3)];
    }
#pragma unroll
    for (int m = 0; m < 4; ++m)
#pragma unroll
      for (int n = 0; n < 4; ++n)
        acc[m][n] = __builtin_amdgcn_mfma_f32_16x16x32_bf16(af[m], bf[n], acc[m][n], 0, 0, 0);
  };

  const int nt = K >> 5;
  stage(0, 0);
  __syncthreads();
  int cur = 0;
  for (int t = 0; t < nt - 1; ++t) {
    stage(cur ^ 1, t + 1);      // prefetch next tile (latency hides under compute)
    compute(cur);
    __syncthreads();            // drains vmcnt(0)+lgkmcnt(0): next tile ready
    cur ^= 1;
  }
  compute(cur);

  const int r4 = (lane >> 4) * 4;
#pragma unroll
  for (int m = 0; m < 4; ++m) {
#pragma unroll
    for (int j = 0; j < 4; ++j) {
      const int row = bm + wr * 64 + m * 16 + r4 + j;
      if (row >= M) continue;
#pragma unroll
      for (int n = 0; n < 4; ++n) {
        const int cn = bn + wc * 64 + n * 16 + col;
        float v = acc[m][n][j];
        if (flags & 1) v += bias[cn];
        if (flags & 2) v = fmaxf(v, 0.f);
        if (flags & 4) v += Rp[(long long)row * N + cn];
        if (flags & 8) Cb[(long long)row * N + cn] = f2bu(v);
        else           Cf[(long long)row * N + cn] = v;
      }
    }
  }
}

// ============================================================================
// fp32 SGEMM (stage-1 scores only)
// ============================================================================
__global__ __launch_bounds__(256) void gemm_k(
    const float* __restrict__ Ap, long long a_base, int a_rs, int a_cs, long long a_zs,
    const float* __restrict__ Wp, long long w_base, int w_rs, int w_cs, long long w_zs,
    const float* __restrict__ bias,
    const float* Rp, int r_rs, long long r_zs,
    float* Cp, long long c_base, int c_rs, long long c_zs,
    int M, int N, int K, float alpha, int flags)
{
  __shared__ float As[8][132];
  __shared__ float Bs[8][132];
  const int z = blockIdx.z;
  const float* A = Ap + a_base + (long long)z * a_zs;
  const float* W = Wp + w_base + (long long)z * w_zs;
  float* C = Cp + c_base + (long long)z * c_zs;
  const float* R = (flags & 4) ? (Rp + (long long)z * r_zs) : nullptr;

  const int bm = blockIdx.y * 128;
  const int bn = blockIdx.x * 128;
  const int tid = threadIdx.x;
  const int tx = tid & 15;
  const int ty = tid >> 4;
  const int srow = tid >> 1;
  const int k4 = (tid & 1) * 4;

  float acc[8][8];
#pragma unroll
  for (int i = 0; i < 8; ++i)
#pragma unroll
    for (int j = 0; j < 8; ++j) acc[i][j] = 0.f;

  const int am = bm + srow;
  const int wn = bn + srow;
  const bool am_ok = am < M;
  const bool wn_ok = wn < N;
  const long long aoff = (long long)(am_ok ? am : 0) * a_rs;
  const long long woff = (long long)(wn_ok ? wn : 0) * w_rs;

  for (int k0 = 0; k0 < K; k0 += 8) {
    if (a_cs == 1 && am_ok && (k0 + 8 <= K)) {
      float4 v = *(const float4*)(A + aoff + k0 + k4);
      As[k4+0][srow] = v.x; As[k4+1][srow] = v.y;
      As[k4+2][srow] = v.z; As[k4+3][srow] = v.w;
    } else {
#pragma unroll
      for (int j = 0; j < 4; ++j) {
        int kk = k0 + k4 + j;
        float va = 0.f;
        if (am_ok && kk < K) va = A[aoff + (long long)kk * a_cs];
        As[k4+j][srow] = va;
      }
    }
    if (w_cs == 1 && wn_ok && (k0 + 8 <= K)) {
      float4 v = *(const float4*)(W + woff + k0 + k4);
      Bs[k4+0][srow] = v.x; Bs[k4+1][srow] = v.y;
      Bs[k4+2][srow] = v.z; Bs[k4+3][srow] = v.w;
    } else {
#pragma unroll
      for (int j = 0; j < 4; ++j) {
        int kk = k0 + k4 + j;
        float vb = 0.f;
        if (wn_ok && kk < K) vb = W[woff + (long long)kk * w_cs];
        Bs[k4+j][srow] = vb;
      }
    }
    __syncthreads();
#pragma unroll
    for (int kk = 0; kk < 8; ++kk) {
      float af[8], bf[8];
      *(float4*)&af[0] = *(const float4*)&As[kk][ty*8];
      *(float4*)&af[4] = *(const float4*)&As[kk][ty*8+4];
      *(float4*)&bf[0] = *(const float4*)&Bs[kk][tx*4];
      *(float4*)&bf[4] = *(const float4*)&Bs[kk][64+tx*4];
#pragma unroll
      for (int i = 0; i < 8; ++i)
#pragma unroll
        for (int j = 0; j < 8; ++j)
          acc[i][j] = fmaf(af[i], bf[j], acc[i][j]);
    }
    __syncthreads();
  }

#pragma unroll
  for (int i = 0; i < 8; ++i) {
    int m = bm + ty*8 + i;
    if (m >= M) continue;
#pragma unroll
    for (int jg = 0; jg < 2; ++jg) {
#pragma unroll
      for (int j = 0; j < 4; ++j) {
        int n = bn + jg*64 + tx*4 + j;
        if (n >= N) continue;
        float v = acc[i][jg*4+j] * alpha;
        if (flags & 1) v += bias[n];
        if (flags & 2) v = fmaxf(v, 0.f);
        if (flags & 4) v += R[(long long)m * r_rs + n];
        C[(long long)m * c_rs + n] = v;
      }
    }
  }
}

// ============================================================================
// Split-K fp32 GEMM partial + reduce
// ============================================================================
__global__ __launch_bounds__(256) void gemm_sk_k(
    const float* __restrict__ Ap, long long a_base, int a_rs, int a_cs, long long a_zs,
    const float* __restrict__ Wp, long long w_base, int w_rs, int w_cs, long long w_zs,
    float* __restrict__ P,
    int M, int N, int K, int KS)
{
  __shared__ float As[8][132];
  __shared__ float Bs[8][132];
  const int zks = blockIdx.z;
  const int z = zks / KS, ks = zks % KS;
  const int klen = (K + KS - 1) / KS;
  const int kbeg = ks * klen;
  const int kend = min(K, kbeg + klen);
  const float* A = Ap + a_base + (long long)z * a_zs;
  const float* W = Wp + w_base + (long long)z * w_zs;

  const int bm = blockIdx.y * 128;
  const int bn = blockIdx.x * 128;
  const int tid = threadIdx.x;
  const int tx = tid & 15;
  const int ty = tid >> 4;
  const int srow = tid >> 1;
  const int k4 = (tid & 1) * 4;

  float acc[8][8];
#pragma unroll
  for (int i = 0; i < 8; ++i)
#pragma unroll
    for (int j = 0; j < 8; ++j) acc[i][j] = 0.f;

  const int am = bm + srow;
  const int wn = bn + srow;
  const bool am_ok = am < M;
  const bool wn_ok = wn < N;
  const long long aoff = (long long)(am_ok ? am : 0) * a_rs;
  const long long woff = (long long)(wn_ok ? wn : 0) * w_rs;

  for (int k0 = kbeg; k0 < kend; k0 += 8) {
    if (a_cs == 1 && am_ok && (k0 + 8 <= kend)) {
      float4 v = *(const float4*)(A + aoff + k0 + k4);
      As[k4+0][srow] = v.x; As[k4+1][srow] = v.y;
      As[k4+2][srow] = v.z; As[k4+3][srow] = v.w;
    } else {
#pragma unroll
      for (int j = 0; j < 4; ++j) {
        int kk = k0 + k4 + j;
        float va = 0.f;
        if (am_ok && kk < kend) va = A[aoff + (long long)kk * a_cs];
        As[k4+j][srow] = va;
      }
    }
    if (w_cs == 1 && wn_ok && (k0 + 8 <= kend)) {
      float4 v = *(const float4*)(W + woff + k0 + k4);
      Bs[k4+0][srow] = v.x; Bs[k4+1][srow] = v.y;
      Bs[k4+2][srow] = v.z; Bs[k4+3][srow] = v.w;
    } else {
#pragma unroll
      for (int j = 0; j < 4; ++j) {
        int kk = k0 + k4 + j;
        float vb = 0.f;
        if (wn_ok && kk < kend) vb = W[woff + (long long)kk * w_cs];
        Bs[k4+j][srow] = vb;
      }
    }
    __syncthreads();
#pragma unroll
    for (int kk = 0; kk < 8; ++kk) {
      float af[8], bf[8];
      *(float4*)&af[0] = *(const float4*)&As[kk][ty*8];
      *(float4*)&af[4] = *(const float4*)&As[kk][ty*8+4];
      *(float4*)&bf[0] = *(const float4*)&Bs[kk][tx*4];
      *(float4*)&bf[4] = *(const float4*)&Bs[kk][64+tx*4];
#pragma unroll
      for (int i = 0; i < 8; ++i)
#pragma unroll
        for (int j = 0; j < 8; ++j)
          acc[i][j] = fmaf(af[i], bf[j], acc[i][j]);
    }
    __syncthreads();
  }

  float* Pz = P + ((long long)zks * M) * N;
#pragma unroll
  for (int i = 0; i < 8; ++i) {
    int m = bm + ty*8 + i;
    if (m >= M) continue;
#pragma unroll
    for (int jg = 0; jg < 2; ++jg) {
#pragma unroll
      for (int j = 0; j < 4; ++j) {
        int n = bn + jg*64 + tx*4 + j;
        if (n >= N) continue;
        Pz[(long long)m * N + n] = acc[i][jg*4+j];
      }
    }
  }
}

__global__ __launch_bounds__(256) void sk_reduce_k(
    const float* __restrict__ P, int M, int N, int KS, float alpha,
    const float* __restrict__ bias, const float* Rp, int r_rs, long long r_zs,
    float* Cp, long long c_base, int c_rs, long long c_zs, int flags)
{
  long long idx = (long long)blockIdx.x * 256 + threadIdx.x;
  if (idx >= (long long)M * N) return;
  const int z = blockIdx.y;
  const int m = (int)(idx / N), n = (int)(idx % N);
  const long long mn = (long long)M * N;
  const float* p = P + (long long)z * KS * mn + idx;
  float s = 0.f;
  for (int ks = 0; ks < KS; ++ks) s += p[(long long)ks * mn];
  s *= alpha;
  if (flags & 1) s += bias[n];
  if (flags & 2) s = fmaxf(s, 0.f);
  if (flags & 4) s += Rp[(long long)z * r_zs + (long long)m * r_rs + n];
  Cp[c_base + (long long)z * c_zs + (long long)m * c_rs + n] = s;
}

// tall-skinny head: out[m, 0..N) = A[m,:512] . W[n,:512] + bias, N <= 8
__global__ __launch_bounds__(256) void head_k(
    const float* __restrict__ A, const float* __restrict__ W,
    const float* __restrict__ bias, float* __restrict__ out, int N)
{
  __shared__ float red[4][8];
  const int m = blockIdx.x;
  const int tid = threadIdx.x, lane = tid & 63, w = tid >> 6;
  const float a0 = A[(long long)m * 512 + tid];
  const float a1 = A[(long long)m * 512 + tid + 256];
  for (int n = 0; n < N; ++n) {
    float p = a0 * W[n*512 + tid] + a1 * W[n*512 + tid + 256];
#pragma unroll
    for (int off = 32; off > 0; off >>= 1) p += __shfl_down(p, off, 64);
    if (lane == 0) red[w][n] = p;
  }
  __syncthreads();
  if (tid < N) out[(long long)m * N + tid] = red[0][tid]+red[1][tid]+red[2][tid]+red[3][tid] + bias[tid];
}

// ============================================================================
// LayerNorm over E=512; fused add of up to 2 extras; optional relu;
// writes fp32 to outp (if non-null) and/or bf16 to outb (if non-null).
// ============================================================================
__global__ __launch_bounds__(256) void ln_k(
    const float* __restrict__ in0, const float* __restrict__ in1, const float* __restrict__ in2,
    const float* __restrict__ g, const float* __restrict__ b,
    float* __restrict__ outp, ushort* __restrict__ outb, int relu)
{
  __shared__ float red[8];
  const long long base = (long long)blockIdx.x * 512;
  const int tid = threadIdx.x;
  float x0 = in0[base + tid];
  float x1 = in0[base + tid + 256];
  if (in1) { x0 += in1[base + tid]; x1 += in1[base + tid + 256]; }
  if (in2) { x0 += in2[base + tid]; x1 += in2[base + tid + 256]; }
  float s = x0 + x1, q = x0*x0 + x1*x1;
#pragma unroll
  for (int off = 32; off > 0; off >>= 1) {
    s += __shfl_down(s, off, 64);
    q += __shfl_down(q, off, 64);
  }
  if ((tid & 63) == 0) { red[tid >> 6] = s; red[4 + (tid >> 6)] = q; }
  __syncthreads();
  if (tid == 0) {
    float S = red[0]+red[1]+red[2]+red[3];
    float Q = red[4]+red[5]+red[6]+red[7];
    float m = S * (1.f/512.f);
    float v = Q * (1.f/512.f) - m*m;
    red[0] = m; red[1] = rsqrtf(v + 1e-5f);
  }
  __syncthreads();
  float m = red[0], inv = red[1];
  float y0 = (x0 - m) * inv * g[tid]     + b[tid];
  float y1 = (x1 - m) * inv * g[tid+256] + b[tid+256];
  if (relu) { y0 = fmaxf(y0, 0.f); y1 = fmaxf(y1, 0.f); }
  if (outp) {
    outp[base + tid]       = y0;
    outp[base + tid + 256] = y1;
  }
  if (outb) {
    outb[base + tid]       = f2bu(y0);
    outb[base + tid + 256] = f2bu(y1);
  }
}

__global__ __launch_bounds__(256) void softmax_k(float* __restrict__ p, int S)
{
  __shared__ float red[8];
  float* r = p + (long long)blockIdx.x * S;
  const int tid = threadIdx.x;
  float vals[4];
  int cnt = 0;
  float mx = -3.0e38f;
  for (int e = tid; e < S; e += 256) { float v = r[e]; vals[cnt++] = v; mx = fmaxf(mx, v); }
#pragma unroll
  for (int off = 32; off > 0; off >>= 1) mx = fmaxf(mx, __shfl_down(mx, off, 64));
  if ((tid & 63) == 0) red[tid >> 6] = mx;
  __syncthreads();
  if (tid == 0) red[0] = fmaxf(fmaxf(red[0], red[1]), fmaxf(red[2], red[3]));
  __syncthreads();
  mx = red[0];
  float sum = 0.f;
  for (int i = 0; i < cnt; ++i) { vals[i] = expf(vals[i] - mx); sum += vals[i]; }
#pragma unroll
  for (int off = 32; off > 0; off >>= 1) sum += __shfl_down(sum, off, 64);
  if ((tid & 63) == 0) red[4 + (tid >> 6)] = sum;
  __syncthreads();
  if (tid == 0) red[4] = red[4]+red[5]+red[6]+red[7];
  __syncthreads();
  float inv = 1.f / red[4];
  cnt = 0;
  for (int e = tid; e < S; e += 256) r[e] = vals[cnt++] * inv;
}

__global__ __launch_bounds__(256) void softmax4_k(float* __restrict__ p, int rows)
{
  int i = blockIdx.x * 256 + threadIdx.x;
  if (i >= rows) return;
  float* r = p + (long long)i * 4;
  float m = fmaxf(fmaxf(r[0], r[1]), fmaxf(r[2], r[3]));
  float e0 = expf(r[0]-m), e1 = expf(r[1]-m), e2 = expf(r[2]-m), e3 = expf(r[3]-m);
  float inv = 1.f / (e0+e1+e2+e3);
  r[0] = e0*inv; r[1] = e1*inv; r[2] = e2*inv; r[3] = e3*inv;
}

__global__ __launch_bounds__(256) void add2_k(
    const float* __restrict__ a, const float* __restrict__ b, float* __restrict__ o, int n)
{
  int i = blockIdx.x * 256 + threadIdx.x;
  if (i < n) o[i] = a[i] + b[i];
}

__global__ __launch_bounds__(256) void f2b_k(
    const float* __restrict__ in, ushort* __restrict__ out, int n)
{
  int i = blockIdx.x * 256 + threadIdx.x;
  if (i < n) out[i] = f2bu(in[i]);
}

DEVI float inv_sig(float x)
{
  x = fminf(fmaxf(x, 0.f), 1.f);
  float a = fmaxf(x, 1e-5f);
  float c = fmaxf(1.f - x, 1e-5f);
  return logf(a / c);
}

__global__ __launch_bounds__(256) void sample_prep_k(
    const float* __restrict__ ref, const float* __restrict__ offs,
    const float* __restrict__ proj, float* __restrict__ camxy, float* __restrict__ valid)
{
  int n = blockIdx.x * 256 + threadIdx.x;
  if (n >= 3600) return;
  int qq = n >> 2, pp = n & 3;
  int rrow = n % 900;
  float tx = inv_sig(ref[rrow*2+0]) + offs[qq*8 + pp*2 + 0];
  float ty = inv_sig(ref[rrow*2+1]) + offs[qq*8 + pp*2 + 1];
  float sx = 1.f / (1.f + expf(-tx));
  float sy = 1.f / (1.f + expf(-ty));
  float px = sx * 480.f, py = sy * 1440.f;
#pragma unroll
  for (int c = 0; c < 7; ++c) {
    const float* M = proj + c*9;
    float icx = M[0]*px + M[1]*py + M[2];
    float icy = M[3]*px + M[4]*py + M[5];
    float icz = M[6]*px + M[7]*py + M[8];
    float zc = fmaxf(icz, 1e-5f);
    float cx = (icx/zc/1920.f - 0.5f) * 2.f;
    float cy = (icy/zc/1080.f - 0.5f) * 2.f;
    int ok = (icz > 1e-5f) && (cx > -1.f) && (cx < 1.f) && (cy > -1.f) && (cy < 1.f);
    camxy[((long long)c*3600+n)*2+0] = cx;
    camxy[((long long)c*3600+n)*2+1] = cy;
    valid[(long long)c*3600+n] = ok ? 1.f : 0.f;
  }
}

// img [7][512][8160] fp32 -> imgT [7][8160][512] bf16
__global__ __launch_bounds__(256) void timg_k(
    const float* __restrict__ img, ushort* __restrict__ out)
{
  __shared__ float t[32][33];
  const int cam = blockIdx.z;
  const int hw0 = blockIdx.x * 32;
  const int c0  = blockIdx.y * 32;
  const int tx = threadIdx.x & 31, ty = threadIdx.x >> 5;
  const float* src = img + ((long long)cam * 512 + c0) * 8160 + hw0;
#pragma unroll
  for (int i = 0; i < 4; ++i)
    t[ty + i*8][tx] = src[(long long)(ty + i*8) * 8160 + tx];
  __syncthreads();
  ushort* dst = out + ((long long)cam * 8160 + hw0) * 512 + c0;
#pragma unroll
  for (int i = 0; i < 4; ++i)
    dst[(long long)(ty + i*8) * 512 + tx] = f2bu(t[tx][ty + i*8]);
}

__global__ __launch_bounds__(128) void grid_sample2_k(
    const ushort* __restrict__ imgT, const float* __restrict__ camxy,
    float* __restrict__ xout)
{
  const int blk = blockIdx.x;
  const int pt = blk / 7, cam = blk % 7;
  float gx = camxy[((long long)cam*3600+pt)*2+0];
  float gy = camxy[((long long)cam*3600+pt)*2+1];
  float fx = (gx + 1.f) * 60.f - 0.5f;
  float fy = (gy + 1.f) * 34.f - 0.5f;
  float x0f = floorf(fx), y0f = floorf(fy);
  float wx1 = fx - x0f, wy1 = fy - y0f;
  float wx0 = 1.f - wx1, wy0 = 1.f - wy1;
  x0f = fminf(fmaxf(x0f, -2.e9f), 2.e9f);
  y0f = fminf(fmaxf(y0f, -2.e9f), 2.e9f);
  int x0 = (int)x0f, y0 = (int)y0f;
  int x1 = x0 + 1, y1 = y0 + 1;
  bool okx0 = (x0 >= 0) && (x0 < 120);
  bool okx1 = (x1 >= 0) && (x1 < 120);
  bool oky0 = (y0 >= 0) && (y0 < 68);
  bool oky1 = (y1 >= 0) && (y1 < 68);
  int cx0 = min(max(x0,0),119), cx1 = min(max(x1,0),119);
  int cy0 = min(max(y0,0),67),  cy1 = min(max(y1,0),67);
  float w00 = (okx0 && oky0) ? wy0*wx0 : 0.f;
  float w01 = (okx1 && oky0) ? wy0*wx1 : 0.f;
  float w10 = (okx0 && oky1) ? wy1*wx0 : 0.f;
  float w11 = (okx1 && oky1) ? wy1*wx1 : 0.f;
  const long long i00 = (long long)(cy0*120+cx0) * 512;
  const long long i01 = (long long)(cy0*120+cx1) * 512;
  const long long i10 = (long long)(cy1*120+cx0) * 512;
  const long long i11 = (long long)(cy1*120+cx1) * 512;
  const ushort* f = imgT + (long long)cam * 8160 * 512;
  float* o = xout + (long long)blk * 512;
  const int c = threadIdx.x * 4;
  ushort4 u00 = *(const ushort4*)(f + i00 + c);
  ushort4 u01 = *(const ushort4*)(f + i01 + c);
  ushort4 u10 = *(const ushort4*)(f + i10 + c);
  ushort4 u11 = *(const ushort4*)(f + i11 + c);
  float4 r;
  r.x = b2f(u00.x)*w00 + b2f(u01.x)*w01 + b2f(u10.x)*w10 + b2f(u11.x)*w11;
  r.y = b2f(u00.y)*w00 + b2f(u01.y)*w01 + b2f(u10.y)*w10 + b2f(u11.y)*w11;
  r.z = b2f(u00.z)*w00 + b2f(u01.z)*w01 + b2f(u10.z)*w10 + b2f(u11.z)*w11;
  r.w = b2f(u00.w)*w00 + b2f(u01.w)*w01 + b2f(u10.w)*w10 + b2f(u11.w)*w11;
  *(float4*)(o + c) = r;
}

// Per-batch 7-token MHA; qkv bf16 chunk rows; out bf16 at GLOBAL rows.
__global__ __launch_bounds__(256) void tf_attn_k(
    const ushort* __restrict__ qkv, const float* __restrict__ valid,
    ushort* __restrict__ outp, int batch0)
{
  __shared__ ushort sv[7*1536];
  const int lb = blockIdx.x;
  const int ib = batch0 + lb;
  const uint4* src = (const uint4*)(qkv + (long long)lb * (7*1536));
  uint4* dst4 = (uint4*)sv;
  for (int idx = threadIdx.x; idx < 7*1536/8; idx += 256) dst4[idx] = src[idx];
  __syncthreads();
  const int tid = threadIdx.x;
  if (tid < 56) {
    const int h = tid / 7, sq = tid % 7;
    const int bb = ib*8 + h;
    const int pp = bb / 7200;
    const int rr = (bb - pp*7200) % 900;
    float qv[64];
    {
      const ushort* qrow = sv + sq*1536 + h*64;
#pragma unroll
      for (int e4 = 0; e4 < 16; ++e4) {
        ushort4 u = *(const ushort4*)(qrow + e4*4);
        qv[e4*4+0] = b2f(u.x); qv[e4*4+1] = b2f(u.y);
        qv[e4*4+2] = b2f(u.z); qv[e4*4+3] = b2f(u.w);
      }
    }
    float sc[7];
    float mx = -3.0e38f;
#pragma unroll
    for (int t = 0; t < 7; ++t) {
      const ushort* krow = sv + t*1536 + 512 + h*64;
      float d = 0.f;
#pragma unroll
      for (int e4 = 0; e4 < 16; ++e4) {
        ushort4 u = *(const ushort4*)(krow + e4*4);
        d = fmaf(qv[e4*4+0], b2f(u.x), d);
        d = fmaf(qv[e4*4+1], b2f(u.y), d);
        d = fmaf(qv[e4*4+2], b2f(u.z), d);
        d = fmaf(qv[e4*4+3], b2f(u.w), d);
      }
      d *= 0.125f;
      if (valid[(long long)t*3600 + rr*4 + pp] == 0.f) d = -1e9f;
      sc[t] = d;
      mx = fmaxf(mx, d);
    }
    float sum = 0.f;
#pragma unroll
    for (int t = 0; t < 7; ++t) { sc[t] = expf(sc[t] - mx); sum += sc[t]; }
    float inv = 1.f / sum;
#pragma unroll
    for (int t = 0; t < 7; ++t) sc[t] *= inv;
    ushort* orow = outp + ((long long)ib*7 + sq)*512 + h*64;
    for (int e = 0; e < 64; e += 4) {
      float a0=0.f, a1=0.f, a2=0.f, a3=0.f;
#pragma unroll
      for (int t = 0; t < 7; ++t) {
        ushort4 u = *(const ushort4*)(sv + t*1536 + 1024 + h*64 + e);
        float w = sc[t];
        a0 = fmaf(w, b2f(u.x), a0); a1 = fmaf(w, b2f(u.y), a1);
        a2 = fmaf(w, b2f(u.z), a2); a3 = fmaf(w, b2f(u.w), a3);
      }
      ushort4 st;
      st.x = f2bu(a0); st.y = f2bu(a1); st.z = f2bu(a2); st.w = f2bu(a3);
      *(ushort4*)orow = st;
      orow += 4;
    }
  }
}

// pooled (bf16 out for MFMA consumption)
__global__ __launch_bounds__(256) void pool_k(
    const float* __restrict__ x, const float* __restrict__ aw, ushort* __restrict__ o)
{
  int qq = blockIdx.x;
  for (int c = threadIdx.x; c < 512; c += 256) {
    float acc = 0.f;
#pragma unroll
    for (int p = 0; p < 4; ++p) {
      const float* xr = x + ((long long)(qq*4+p)*7)*512 + c;
      float s = 0.f;
#pragma unroll
      for (int cam = 0; cam < 7; ++cam) s += xr[cam*512];
      acc = fmaf(s, aw[qq*4+p], acc);
    }
    o[(long long)qq*512 + c] = f2bu(acc * (1.f/28.f));
  }
}

__global__ __launch_bounds__(256) void pe1_k(
    const float* __restrict__ ref, const float* __restrict__ w1, const float* __restrict__ b1,
    float* __restrict__ o)
{
  int idx = blockIdx.x * 256 + threadIdx.x;
  if (idx >= 900*512) return;
  int qq = idx >> 9, c = idx & 511;
  float i0 = inv_sig(ref[qq*2+0]);
  float i1 = inv_sig(ref[qq*2+1]);
  o[idx] = i0*w1[c*2+0] + i1*w1[c*2+1] + b1[c];
}

// ============================================================================
extern "C" void kernel_launch(void* const* d_in, const int* in_sizes, int n_in,
                              void* d_out, int out_size, void* d_ws, size_t ws_size,
                              hipStream_t stream)
{
  (void)in_sizes; (void)n_in; (void)out_size;
  const float* img      = (const float*)d_in[0];
  const float* proj     = (const float*)d_in[1];
  const float* query    = (const float*)d_in[2];
  const float* qpos     = (const float*)d_in[3];
  const float* ref      = (const float*)d_in[4];
  const float* mha_in_w = (const float*)d_in[5];
  const float* mha_in_b = (const float*)d_in[6];
  const float* mha_out_w= (const float*)d_in[7];
  const float* mha_out_b= (const float*)d_in[8];
  const float* off_w1   = (const float*)d_in[9];
  const float* off_b1   = (const float*)d_in[10];
  const float* off_w2   = (const float*)d_in[11];
  const float* off_b2   = (const float*)d_in[12];
  const float* am_w1    = (const float*)d_in[13];
  const float* am_b1    = (const float*)d_in[14];
  const float* am_w2    = (const float*)d_in[15];
  const float* am_b2    = (const float*)d_in[16];
  const float* t_ln1_g  = (const float*)d_in[17];
  const float* t_ln1_b  = (const float*)d_in[18];
  const float* t_in_w   = (const float*)d_in[19];
  const float* t_in_b   = (const float*)d_in[20];
  const float* t_out_w  = (const float*)d_in[21];
  const float* t_out_b  = (const float*)d_in[22];
  const float* t_ln2_g  = (const float*)d_in[23];
  const float* t_ln2_b  = (const float*)d_in[24];
  const float* t_ff_w1  = (const float*)d_in[25];
  const float* t_ff_b1  = (const float*)d_in[26];
  const float* t_ff_w2  = (const float*)d_in[27];
  const float* t_ff_b2  = (const float*)d_in[28];
  const float* ffn_w1   = (const float*)d_in[29];
  const float* ffn_b1   = (const float*)d_in[30];
  const float* ffn_w2   = (const float*)d_in[31];
  const float* ffn_b2   = (const float*)d_in[32];
  const float* op_w     = (const float*)d_in[33];
  const float* op_b     = (const float*)d_in[34];
  const float* pe_w1    = (const float*)d_in[35];
  const float* pe_bias1 = (const float*)d_in[36];
  const float* pe_ln1_g = (const float*)d_in[37];
  const float* pe_ln1_b = (const float*)d_in[38];
  const float* pe_w2    = (const float*)d_in[39];
  const float* pe_bias2 = (const float*)d_in[40];
  const float* pe_ln2_g = (const float*)d_in[41];
  const float* pe_ln2_b = (const float*)d_in[42];
  const float* ln1_g    = (const float*)d_in[43];
  const float* ln1_b    = (const float*)d_in[44];
  const float* ln2_g    = (const float*)d_in[45];
  const float* ln2_b    = (const float*)d_in[46];
  const float* ln3_g    = (const float*)d_in[47];
  const float* ln3_b    = (const float*)d_in[48];

  char* wsb = (char*)d_ws;
  size_t off = 0;
  auto alloc = [&](long long bytes) -> char* {
    char* p = wsb + off;
    off += (size_t)((bytes + 255) / 256 * 256);
    return p;
  };
  float* X    = (float*)alloc(25200ll * 512 * 4);      // tokens; SC + split-K partials overlay pre-sample
  float* QKV  = (float*)alloc(4200ll * 1536 * 4);      // stage-1 qkv fp32; transformer QKVh bf16 overlay
  char*  R1   = alloc(7ll * 8160 * 512 * 2);
  ushort* imgT = (ushort*)R1;
  ushort* XNh  = (ushort*)R1;                          // [25344][512]
  ushort* Hh   = (ushort*)(R1 + 25344ll * 512 * 2);
  ushort* Wqkvh = (ushort*)alloc(4ll * 1536 * 512 * 2);
  ushort* Wouth = (ushort*)alloc(4ll * 512 * 512 * 2);
  ushort* Wff1h = (ushort*)alloc(4ll * 512 * 512 * 2);
  ushort* Wff2h = (ushort*)alloc(4ll * 512 * 512 * 2);
  ushort* Wtailh = (ushort*)alloc(4ll * 512 * 512 * 2); // op_w, pe_w2, ffn_w1, ffn_w2
  ushort* PoolH = (ushort*)alloc(1024ll * 512 * 2);
  ushort* PEh   = (ushort*)alloc(1024ll * 512 * 2);
  ushort* S3h   = (ushort*)alloc(1024ll * 512 * 2);
  ushort* Hh2   = (ushort*)alloc(1024ll * 512 * 2);
  float* S0   = (float*)alloc(900ll * 512 * 4);
  float* S1   = (float*)alloc(900ll * 512 * 4);
  float* S2   = (float*)alloc(900ll * 512 * 4);
  float* S3   = (float*)alloc(900ll * 512 * 4);
  float* S4   = (float*)alloc(900ll * 512 * 4);
  float* S5   = (float*)alloc(900ll * 512 * 4);
  float* OFFB = (float*)alloc(900ll * 8 * 4);
  float* AMB  = (float*)alloc(900ll * 4 * 4);
  float* CXY  = (float*)alloc(7ll * 3600 * 2 * 4);
  float* VAL  = (float*)alloc(7ll * 3600 * 4);
  if (off > ws_size) return;

  float* SC  = X;                 // [8][900][900] scores (dead before sampling)
  float* P1  = X;                 // qkv1 split-K partials
  float* P2  = X + 6500000;       // split-K partials while SC live
  float* QKV1 = QKV;              // stage-1 fp32 view
  ushort* QKVh = (ushort*)QKV;    // transformer bf16 view (stage-1 dead by then)

  auto gemm = [&](const float* A, long long ab, int ars, int acs, long long azs,
                  const float* W, long long wb, int wrs, int wcs, long long wzs,
                  const float* bias, const float* R, int rrs, long long rzs,
                  float* C, long long cb, int crs, long long czs,
                  int M, int N, int K, float alpha, int flags, int Z) {
    dim3 grd((unsigned)((N + 127) / 128), (unsigned)((M + 127) / 128), (unsigned)Z);
    gemm_k<<<grd, dim3(256), 0, stream>>>(A, ab, ars, acs, azs, W, wb, wrs, wcs, wzs,
                                          bias, R, rrs, rzs, C, cb, crs, czs,
                                          M, N, K, alpha, flags);
  };
  auto skgemm = [&](const float* A, long long ab, int ars, int acs, long long azs,
                    const float* W, long long wb, int wrs, int wcs, long long wzs,
                    float* P, const float* bias, const float* R, int rrs, long long rzs,
                    float* C, long long cb, int crs, long long czs,
                    int M, int N, int K, float alpha, int flags, int Z, int KS) {
    dim3 grd((unsigned)((N + 127) / 128), (unsigned)((M + 127) / 128), (unsigned)(Z * KS));
    gemm_sk_k<<<grd, dim3(256), 0, stream>>>(A, ab, ars, acs, azs, W, wb, wrs, wcs, wzs,
                                             P, M, N, K, KS);
    dim3 grd2((unsigned)(((long long)M * N + 255) / 256), (unsigned)Z);
    sk_reduce_k<<<grd2, dim3(256), 0, stream>>>(P, M, N, KS, alpha, bias, R, rrs, rzs,
                                                C, cb, crs, czs, flags);
  };
  auto mgemm = [&](const ushort* A, const ushort* W, const float* bias,
                   const float* R, float* Cf, ushort* Cb,
                   int M, int N, int K, int flags) {
    dim3 grd((unsigned)(N / 128), (unsigned)((M + 127) / 128), 1);
    gemm_mfma_k<<<grd, dim3(256), 0, stream>>>(A, W, bias, R, Cf, Cb, M, N, K, flags);
  };

  // weight conversion
  f2b_k<<<(4*1536*512+255)/256, 256, 0, stream>>>(t_in_w,  Wqkvh, 4*1536*512);
  f2b_k<<<(4*512*512+255)/256, 256, 0, stream>>>(t_out_w, Wouth, 4*512*512);
  f2b_k<<<(4*512*512+255)/256, 256, 0, stream>>>(t_ff_w1, Wff1h, 4*512*512);
  f2b_k<<<(4*512*512+255)/256, 256, 0, stream>>>(t_ff_w2, Wff2h, 4*512*512);
  f2b_k<<<(512*512+255)/256, 256, 0, stream>>>(op_w,   Wtailh + 0ll*512*512, 512*512);
  f2b_k<<<(512*512+255)/256, 256, 0, stream>>>(pe_w2,  Wtailh + 1ll*512*512, 512*512);
  f2b_k<<<(512*512+255)/256, 256, 0, stream>>>(ffn_w1, Wtailh + 2ll*512*512, 512*512);
  f2b_k<<<(512*512+255)/256, 256, 0, stream>>>(ffn_w2, Wtailh + 3ll*512*512, 512*512);
  timg_k<<<dim3(255, 16, 7), 256, 0, stream>>>(img, imgT);

  // ---------------- stage 1 (fp32, split-K) ----------------
  add2_k<<<1800, 256, 0, stream>>>(query, qpos, S0, 460800);
  skgemm(S0,0,512,1,0,  mha_in_w,0,512,1,0,  P1, mha_in_b, nullptr,0,0,
         QKV1,0,1536,0,  900,1536,512, 1.f, 1, 1, 8);
  gemm(QKV1,0,1536,1,64,  QKV1,512,1536,1,64,  nullptr, nullptr,0,0,
       SC,0,900,810000,  900,900,64, 0.125f, 0, 8);
  softmax_k<<<7200, 256, 0, stream>>>(SC, 900);
  skgemm(SC,0,900,1,810000,  QKV1,1024,1,1536,64,  P2, nullptr, nullptr,0,0,
         S1,0,512,64,  900,64,900, 1.f, 0, 8, 8);
  skgemm(S1,0,512,1,0,  mha_out_w,0,512,1,0,  P2, mha_out_b, S0,512,0,
         S2,0,512,0,  900,512,512, 1.f, 1|4, 1, 8);
  ln_k<<<900, 256, 0, stream>>>(S2, nullptr, nullptr, ln1_g, ln1_b, S1, nullptr, 0); // qn=S1

  skgemm(S1,0,512,1,0, off_w1,0,512,1,0, P2, off_b1, nullptr,0,0,
         S2,0,512,0, 900,512,512, 1.f, 1|2, 1, 8);
  head_k<<<900, 256, 0, stream>>>(S2, off_w2, off_b2, OFFB, 8);
  skgemm(S1,0,512,1,0, am_w1,0,512,1,0, P2, am_b1, nullptr,0,0,
         S2,0,512,0, 900,512,512, 1.f, 1|2, 1, 8);
  head_k<<<900, 256, 0, stream>>>(S2, am_w2, am_b2, AMB, 4);
  softmax4_k<<<4, 256, 0, stream>>>(AMB, 900);

  sample_prep_k<<<15, 256, 0, stream>>>(ref, OFFB, proj, CXY, VAL);
  grid_sample2_k<<<25200, 128, 0, stream>>>(imgT, CXY, X);

  // ---------------- transformer, depth 4 (bf16 MFMA) ----------------
  for (int L = 0; L < 4; ++L) {
    const float* g1  = t_ln1_g + L*512;  const float* bb1 = t_ln1_b + L*512;
    const float* bq  = t_in_b + L*1536;
    const float* bo  = t_out_b + L*512;
    const float* g2  = t_ln2_g + L*512;  const float* bb2 = t_ln2_b + L*512;
    const float* f1  = t_ff_b1 + L*512;
    const float* f2  = t_ff_b2 + L*512;
    const ushort* wq = Wqkvh + (long long)L*1536*512;
    const ushort* wo = Wouth + (long long)L*512*512;
    const ushort* w1 = Wff1h + (long long)L*512*512;
    const ushort* w2 = Wff2h + (long long)L*512*512;

    ln_k<<<25200, 256, 0, stream>>>(X, nullptr, nullptr, g1, bb1, nullptr, XNh, 0);
    for (int ch = 0; ch < 6; ++ch) {
      mgemm(XNh + (long long)ch*4200*512, wq, bq, nullptr, nullptr, QKVh,
            4200, 1536, 512, 1|8);
      tf_attn_k<<<600, 256, 0, stream>>>(QKVh, VAL, XNh, ch*600);
    }
    mgemm(XNh, wo, bo, X, X, nullptr, 25200, 512, 512, 1|4);
    ln_k<<<25200, 256, 0, stream>>>(X, nullptr, nullptr, g2, bb2, nullptr, XNh, 0);
    mgemm(XNh, w1, f1, nullptr, nullptr, Hh, 25200, 512, 512, 1|2|8);
    mgemm(Hh, w2, f2, X, X, nullptr, 25200, 512, 512, 1|4);
  }

  // ---------------- tail (bf16 MFMA) ----------------
  pool_k<<<900, 256, 0, stream>>>(X, AMB, PoolH);
  mgemm(PoolH, Wtailh + 0ll*512*512, op_b, nullptr, S4, nullptr, 900, 512, 512, 1);
  pe1_k<<<1800, 256, 0, stream>>>(ref, pe_w1, pe_bias1, S2);
  ln_k<<<900, 256, 0, stream>>>(S2, nullptr, nullptr, pe_ln1_g, pe_ln1_b, nullptr, PEh, 1);
  mgemm(PEh, Wtailh + 1ll*512*512, pe_bias2, nullptr, S2, nullptr, 900, 512, 512, 1);
  ln_k<<<900, 256, 0, stream>>>(S2, nullptr, nullptr, pe_ln2_g, pe_ln2_b, S5, nullptr, 1);
  ln_k<<<900, 256, 0, stream>>>(S4, S1, S5, ln2_g, ln2_b, S3, S3h, 0);       // qf
  mgemm(S3h, Wtailh + 2ll*512*512, ffn_b1, nullptr, nullptr, Hh2, 900, 512, 512, 1|2|8);
  mgemm(Hh2, Wtailh + 3ll*512*512, ffn_b2, S3, S4, nullptr, 900, 512, 512, 1|4);
  ln_k<<<900, 256, 0, stream>>>(S4, nullptr, nullptr, ln3_g, ln3_b, (float*)d_out, nullptr, 0);
}